// Round 9
// baseline (356.177 us; speedup 1.0000x reference)
//
#include <hip/hip_runtime.h>
#include <hip/hip_bf16.h>
#include <hip/hip_fp16.h>
#include <math.h>

#define D 128
#define SEG 4096           // edges per block in scat2 (196 blocks; SEG=1024 measured WORSE, r5)
#define BSH 7              // bucket shift: bucket = node >> 7 (128 nodes/bucket)
#define RCAP 4096          // fixed record capacity per bucket
#define ACAP 4096          // fixed adjacency capacity per bucket (8-padded lists; mean ~2560)
#define TRS 133            // LDS transpose row stride (fp32) -> <=2-way bank aliasing (free)

typedef _Float16 half8  __attribute__((ext_vector_type(8)));
typedef _Float16 half4v __attribute__((ext_vector_type(4)));
typedef float    fx4    __attribute__((ext_vector_type(4)));

// ---------------- CSR pass 1 (r7 best-measured form): fused histogram + reservation + scatter.
// 512 threads; int4 edge loads register-cached across phases.
__global__ __launch_bounds__(512) void scat2_kernel(const int* __restrict__ src,
                                                    const int* __restrict__ dst,
                                                    int e, int nb,
                                                    int* __restrict__ gcur1, int* __restrict__ gcur2,
                                                    unsigned int* __restrict__ rec1,
                                                    unsigned int* __restrict__ rec2) {
    __shared__ int h1[512], h2[512], o1[512], o2[512], run1[512], run2[512];
    int tid = threadIdx.x;
    for (int b = tid; b < nb; b += 512) { h1[b] = 0; h2[b] = 0; run1[b] = 0; run2[b] = 0; }
    __syncthreads();
    int s0 = blockIdx.x * SEG;
    int s1 = min(e, s0 + SEG);
    int4 sv4[2], dv4[2];
    int np[2];                       // valid edges in pack (0,4, or tail count)
    #pragma unroll
    for (int it = 0; it < 2; it++) {
        int idx = s0 + (it * 512 + tid) * 4;
        int nv = 0;
        if (idx + 3 < s1) {
            sv4[it] = *(const int4*)&src[idx];
            dv4[it] = *(const int4*)&dst[idx];
            nv = 4;
        } else if (idx < s1) {       // ragged tail
            nv = s1 - idx;
            int sv[4] = {0,0,0,0}, dv[4] = {0,0,0,0};
            for (int k = 0; k < nv; k++) { sv[k] = src[idx + k]; dv[k] = dst[idx + k]; }
            sv4[it] = make_int4(sv[0], sv[1], sv[2], sv[3]);
            dv4[it] = make_int4(dv[0], dv[1], dv[2], dv[3]);
        }
        np[it] = nv;
        int dvv[4] = {dv4[it].x, dv4[it].y, dv4[it].z, dv4[it].w};
        int svv[4] = {sv4[it].x, sv4[it].y, sv4[it].z, sv4[it].w};
        for (int k = 0; k < nv; k++) {
            atomicAdd(&h1[dvv[k] >> BSH], 1);
            atomicAdd(&h2[svv[k] >> BSH], 1);
        }
    }
    __syncthreads();
    for (int b = tid; b < nb; b += 512) {
        o1[b] = atomicAdd(&gcur1[b], h1[b]);
        o2[b] = atomicAdd(&gcur2[b], h2[b]);
    }
    __syncthreads();
    #pragma unroll
    for (int it = 0; it < 2; it++) {
        int nv = np[it];
        int dvv[4] = {dv4[it].x, dv4[it].y, dv4[it].z, dv4[it].w};
        int svv[4] = {sv4[it].x, sv4[it].y, sv4[it].z, sv4[it].w};
        for (int k = 0; k < nv; k++) {
            unsigned int sv = (unsigned int)svv[k];
            unsigned int dv = (unsigned int)dvv[k];
            int b1 = dv >> BSH, b2 = sv >> BSH;
            int p1 = o1[b1] + atomicAdd(&run1[b1], 1);
            if (p1 < RCAP) rec1[(size_t)b1 * RCAP + p1] = (dv << 16) | sv;
            int p2 = o2[b2] + atomicAdd(&run2[b2], 1);
            if (p2 < RCAP) rec2[(size_t)b2 * RCAP + p2] = (sv << 16) | dv;
        }
    }
}

// ---------------- CSR pass 2: per (bucket,dir) LDS-local CSR, 8-padded lists. 256 threads.
__global__ __launch_bounds__(256) void fin_kernel(const unsigned int* __restrict__ rec1,
                                                  const unsigned int* __restrict__ rec2,
                                                  const int* __restrict__ gcur1, const int* __restrict__ gcur2,
                                                  unsigned short* __restrict__ adj1, unsigned short* __restrict__ adj2,
                                                  int* __restrict__ ip1, int* __restrict__ ipe1,
                                                  int* __restrict__ ip2, int* __restrict__ ipe2,
                                                  float* __restrict__ dinv1, float* __restrict__ dinv2,
                                                  int n) {
    __shared__ __align__(16) unsigned int Lrec[RCAP];
    __shared__ __align__(16) unsigned short sadj[ACAP];
    __shared__ int deg[128], pscan[128], cur[128];
    __shared__ int ptot_s;
    int bkt = blockIdx.x;
    int dir = blockIdx.y;
    const unsigned int* rec = dir ? rec2 : rec1;
    const int* gc = dir ? gcur2 : gcur1;
    unsigned short* adj = dir ? adj2 : adj1;
    int* ip  = dir ? ip2 : ip1;
    int* ipe = dir ? ipe2 : ipe1;
    float* dinv = dir ? dinv2 : dinv1;

    int tid = threadIdx.x;
    int cnt = gc[bkt];
    if (cnt > RCAP) cnt = RCAP;
    size_t rbase = (size_t)bkt * RCAP;
    if (tid < 128) { deg[tid] = 0; cur[tid] = 0; }
    for (int i = tid * 4; i < cnt; i += 1024) {
        if (i + 3 < cnt) *(uint4*)&Lrec[i] = *(const uint4*)&rec[rbase + i];
        else for (int k = 0; i + k < cnt; k++) Lrec[i + k] = rec[rbase + i + k];
    }
    __syncthreads();
    int base = bkt << BSH;
    for (int i = tid * 4; i < cnt; i += 1024) {
        int lim = min(4, cnt - i);
        for (int k = 0; k < lim; k++)
            atomicAdd(&deg[(int)(Lrec[i + k] >> 16) - base], 1);
    }
    __syncthreads();
    if (tid < 64) {                      // single-wave scan of 128 padded degrees
        int a = (deg[2 * tid] + 7) & ~7;
        int b = (deg[2 * tid + 1] + 7) & ~7;
        int s = a + b;
        #pragma unroll
        for (int off = 1; off < 64; off <<= 1) {
            int u = __shfl_up(s, off, 64);
            if (tid >= off) s += u;
        }
        pscan[2 * tid + 1] = s;
        pscan[2 * tid]     = s - b;
        if (tid == 63) ptot_s = min(s, ACAP);
    }
    __syncthreads();
    int ptot = ptot_s;
    unsigned int nn = ((unsigned int)n << 16) | (unsigned int)n;
    uint4 fillv = make_uint4(nn, nn, nn, nn);
    for (int i = tid * 8; i < ptot; i += 2048) *(uint4*)&sadj[i] = fillv;   // sentinel fill (ptot % 8 == 0)
    __syncthreads();
    for (int i = tid; i < cnt; i += 256) {
        unsigned int r = Lrec[i];
        int l = (int)(r >> 16) - base;
        int pd = (deg[l] + 7) & ~7;
        int pos = pscan[l] - pd + atomicAdd(&cur[l], 1);
        if (pos < ACAP) sadj[pos] = (unsigned short)(r & 0xffffu);
    }
    __syncthreads();
    int gbase = bkt * ACAP;
    for (int i = tid * 8; i < ptot; i += 2048)
        *(uint4*)&adj[gbase + i] = *(const uint4*)&sadj[i];
    if (tid < 128) {
        int node = base + tid;
        if (node < n) {
            int pd = (deg[tid] + 7) & ~7;
            ip[node]  = gbase + pscan[tid] - pd;
            ipe[node] = gbase + pscan[tid];
            dinv[node] = rsqrtf((float)deg[tid] + 1.0f);
        }
    }
}

// ---------------- weight prep (merged): y=0,1 transpose W1/W2 to fp16 [c][k];
// y=2..5 fp16-convert gates; y=6 zero work (gcur, hs sentinel rows).
__global__ __launch_bounds__(256) void prep_kernel(const float* __restrict__ W1, const float* __restrict__ W2,
                                                   const float* __restrict__ w11, const float* __restrict__ w12,
                                                   const float* __restrict__ w21, const float* __restrict__ w22,
                                                   _Float16* __restrict__ T1, _Float16* __restrict__ T2,
                                                   _Float16* __restrict__ o11, _Float16* __restrict__ o12,
                                                   _Float16* __restrict__ o21, _Float16* __restrict__ o22,
                                                   int* __restrict__ gcur, _Float16* __restrict__ hs1,
                                                   _Float16* __restrict__ hs2, int n) {
    __shared__ float s[32][33];
    int which = blockIdx.y;
    if (which < 2) {
        const float* w = which ? W2 : W1;
        _Float16* t = which ? T2 : T1;
        int tk = (blockIdx.x >> 2) * 32;
        int tc = (blockIdx.x & 3) * 32;
        int lr = threadIdx.x >> 5;
        int lc = threadIdx.x & 31;
        #pragma unroll
        for (int i = 0; i < 32; i += 8)
            s[lr + i][lc] = w[(size_t)(tk + lr + i) * D + tc + lc];
        __syncthreads();
        #pragma unroll
        for (int i = 0; i < 32; i += 8)
            t[(size_t)(tc + lr + i) * D + tk + lc] = (_Float16)s[lc][lr + i];
    } else if (which < 6) {
        int wsel = which - 2;
        const float* w = (wsel == 0) ? w11 : (wsel == 1) ? w12 : (wsel == 2) ? w21 : w22;
        _Float16* o = (wsel == 0) ? o11 : (wsel == 1) ? o12 : (wsel == 2) ? o21 : o22;
        int idx = (blockIdx.x * 256 + threadIdx.x) * 4;
        float4 v = *(const float4*)&w[idx];
        half4v h = {(_Float16)v.x, (_Float16)v.y, (_Float16)v.z, (_Float16)v.w};
        *(half4v*)&o[idx] = h;
    } else {
        int tid = threadIdx.x;
        if (blockIdx.x == 0) {
            #pragma unroll
            for (int k = 0; k < 4; k++) gcur[tid + k * 256] = 0;       // 1024 ints
        } else if (blockIdx.x == 1) {
            if (tid < 128) hs1[(size_t)n * D + tid] = (_Float16)0.f;   // sentinel row
        } else if (blockIdx.x == 2) {
            if (tid < 128) hs2[(size_t)n * D + tid] = (_Float16)0.f;
        }
    }
}

// ------------------------------------------------- MFMA GEMM, fp32 A.
// ONE 16-row tile per wave (was 2): 64 rows/block, 782 blocks -> ~12 waves/CU
// (was 391 blocks = 1.5 blocks/CU, latency-starved). Same per-row math.
__global__ __launch_bounds__(256) void gemm_f32a_kernel(const float* __restrict__ A,
                                                        const _Float16* __restrict__ Wt,
                                                        const float* __restrict__ dinv1,
                                                        const float* __restrict__ dinv2,
                                                        _Float16* __restrict__ hs1,
                                                        _Float16* __restrict__ hs2, int n) {
    __shared__ float trs[4][16 * TRS];
    int tid = threadIdx.x;
    int wv = tid >> 6, lane = tid & 63;
    int m = lane & 15, q = lane >> 4;
    int row0 = blockIdx.x * 64 + wv * 16;
    size_t ar0 = (size_t)min(row0 + m, n - 1) * D;
    fx4 acc[8];
    #pragma unroll
    for (int ct = 0; ct < 8; ct++) acc[ct] = (fx4){0.f, 0.f, 0.f, 0.f};
    #pragma unroll
    for (int ks = 0; ks < 4; ks++) {
        int k0 = ks * 32 + q * 8;
        half8 bf[8];
        #pragma unroll
        for (int ct = 0; ct < 8; ct++)
            bf[ct] = *(const half8*)&Wt[(size_t)(ct * 16 + m) * D + k0];
        float4 u0 = *(const float4*)&A[ar0 + k0];
        float4 u1 = *(const float4*)&A[ar0 + k0 + 4];
        half8 a0 = {(_Float16)u0.x, (_Float16)u0.y, (_Float16)u0.z, (_Float16)u0.w,
                    (_Float16)u1.x, (_Float16)u1.y, (_Float16)u1.z, (_Float16)u1.w};
        #pragma unroll
        for (int ct = 0; ct < 8; ct++)
            acc[ct] = __builtin_amdgcn_mfma_f32_16x16x32_f16(a0, bf[ct], acc[ct], 0, 0, 0);
    }
    float* Wl = trs[wv];
    #pragma unroll
    for (int reg = 0; reg < 4; reg++)
        #pragma unroll
        for (int ct = 0; ct < 8; ct++)
            Wl[(q * 4 + reg) * TRS + ct * 16 + m] = acc[ct][reg];
    int r = row0 + m;
    if (r < n) {
        float s1 = dinv1[r], s2 = dinv2[r];
        size_t rr = (size_t)r * D;
        #pragma unroll
        for (int ks = 0; ks < 4; ks++) {
            int c0 = ks * 32 + q * 8;
            float4 p0 = *(const float4*)&Wl[m * TRS + c0];
            float4 p1 = *(const float4*)&Wl[m * TRS + c0 + 4];
            float pv[8] = {p0.x, p0.y, p0.z, p0.w, p1.x, p1.y, p1.z, p1.w};
            half8 h1v, h2v;
            #pragma unroll
            for (int j = 0; j < 8; j++) {
                h1v[j] = (_Float16)(s1 * pv[j]);
                h2v[j] = (_Float16)(s2 * pv[j]);
            }
            *(half8*)&hs1[rr + c0] = h1v;
            *(half8*)&hs2[rr + c0] = h2v;
        }
    }
}

// ------------------------------------------------- MFMA GEMM, fp16 A (same 16-row/wave structure)
__global__ __launch_bounds__(256) void gemm_f16a_kernel(const _Float16* __restrict__ A,
                                                        const _Float16* __restrict__ Wt,
                                                        const float* __restrict__ dinv1,
                                                        const float* __restrict__ dinv2,
                                                        _Float16* __restrict__ hs1,
                                                        _Float16* __restrict__ hs2, int n) {
    __shared__ float trs[4][16 * TRS];
    int tid = threadIdx.x;
    int wv = tid >> 6, lane = tid & 63;
    int m = lane & 15, q = lane >> 4;
    int row0 = blockIdx.x * 64 + wv * 16;
    size_t ar0 = (size_t)min(row0 + m, n - 1) * D;
    fx4 acc[8];
    #pragma unroll
    for (int ct = 0; ct < 8; ct++) acc[ct] = (fx4){0.f, 0.f, 0.f, 0.f};
    #pragma unroll
    for (int ks = 0; ks < 4; ks++) {
        int k0 = ks * 32 + q * 8;
        half8 bf[8];
        #pragma unroll
        for (int ct = 0; ct < 8; ct++)
            bf[ct] = *(const half8*)&Wt[(size_t)(ct * 16 + m) * D + k0];
        half8 a0 = *(const half8*)&A[ar0 + k0];
        #pragma unroll
        for (int ct = 0; ct < 8; ct++)
            acc[ct] = __builtin_amdgcn_mfma_f32_16x16x32_f16(a0, bf[ct], acc[ct], 0, 0, 0);
    }
    float* Wl = trs[wv];
    #pragma unroll
    for (int reg = 0; reg < 4; reg++)
        #pragma unroll
        for (int ct = 0; ct < 8; ct++)
            Wl[(q * 4 + reg) * TRS + ct * 16 + m] = acc[ct][reg];
    int r = row0 + m;
    if (r < n) {
        float s1 = dinv1[r], s2 = dinv2[r];
        size_t rr = (size_t)r * D;
        #pragma unroll
        for (int ks = 0; ks < 4; ks++) {
            int c0 = ks * 32 + q * 8;
            float4 p0 = *(const float4*)&Wl[m * TRS + c0];
            float4 p1 = *(const float4*)&Wl[m * TRS + c0 + 4];
            float pv[8] = {p0.x, p0.y, p0.z, p0.w, p1.x, p1.y, p1.z, p1.w};
            half8 h1v, h2v;
            #pragma unroll
            for (int j = 0; j < 8; j++) {
                h1v[j] = (_Float16)(s1 * pv[j]);
                h2v[j] = (_Float16)(s2 * pv[j]);
            }
            *(half8*)&hs1[rr + c0] = h1v;
            *(half8*)&hs2[rr + c0] = h2v;
        }
    }
}

// ---------------------------------------- aggregation: pre-scaled rows, plain gather-sum.
// (memory-system-bound; schedule variants measured identical r0/r3/r4 — left as-is)
__global__ __launch_bounds__(256) void aggregate2_kernel(const __half* __restrict__ hs1g,
                                                         const __half* __restrict__ hs2g,
                                                         const int* __restrict__ ip1,
                                                         const int* __restrict__ ipe1,
                                                         const unsigned short* __restrict__ adj1,
                                                         const float* __restrict__ dinv1,
                                                         const int* __restrict__ ip2,
                                                         const int* __restrict__ ipe2,
                                                         const unsigned short* __restrict__ adj2,
                                                         const float* __restrict__ dinv2,
                                                         const float* __restrict__ bias,
                                                         _Float16* __restrict__ out1,
                                                         _Float16* __restrict__ out2, int n) {
    const __half* hs = blockIdx.y ? hs2g : hs1g;
    const int* ip  = blockIdx.y ? ip2 : ip1;
    const int* ipe = blockIdx.y ? ipe2 : ipe1;
    const unsigned short* adj = blockIdx.y ? adj2 : adj1;
    const float* dinv = blockIdx.y ? dinv2 : dinv1;
    _Float16* out = blockIdx.y ? out2 : out1;
    int wid = threadIdx.x >> 6, lane = threadIdx.x & 63;
    int hf = lane >> 5, l32 = lane & 31;
    int i = blockIdx.x * 4 + wid;
    if (i >= n) return;
    int beg = ip[i], endp = ipe[i];
    int fcol = 4 * l32;
    float4 acc = make_float4(0.f, 0.f, 0.f, 0.f);
    if (beg < endp) {
        int hoff = hf << 2;                 // half 0 -> entries j..j+3, half 1 -> j+4..j+7
        int j = beg;
        uint2 iv = *(const uint2*)&adj[j + hoff];
        while (true) {
            int jn = j + 8;
            int jp = jn < endp ? jn : j;    // clamp: last iter re-loads current (independent, no wait)
            uint2 niv = *(const uint2*)&adj[jp + hoff];
            int s0 = iv.x & 0xffff, s1 = iv.x >> 16;
            int s2 = iv.y & 0xffff, s3 = iv.y >> 16;
            uint2 r0 = *(const uint2*)&hs[(s0 << 7) + fcol];
            uint2 r1 = *(const uint2*)&hs[(s1 << 7) + fcol];
            uint2 r2 = *(const uint2*)&hs[(s2 << 7) + fcol];
            uint2 r3 = *(const uint2*)&hs[(s3 << 7) + fcol];
            float2 a0 = __half22float2(*(__half2*)&r0.x), b0 = __half22float2(*(__half2*)&r0.y);
            float2 a1 = __half22float2(*(__half2*)&r1.x), b1 = __half22float2(*(__half2*)&r1.y);
            float2 a2 = __half22float2(*(__half2*)&r2.x), b2 = __half22float2(*(__half2*)&r2.y);
            float2 a3 = __half22float2(*(__half2*)&r3.x), b3 = __half22float2(*(__half2*)&r3.y);
            acc.x += a0.x + a1.x + a2.x + a3.x;
            acc.y += a0.y + a1.y + a2.y + a3.y;
            acc.z += b0.x + b1.x + b2.x + b3.x;
            acc.w += b0.y + b1.y + b2.y + b3.y;
            if (jn >= endp) break;
            iv = niv; j = jn;
        }
    }
    acc.x += __shfl_xor(acc.x, 32, 64);
    acc.y += __shfl_xor(acc.y, 32, 64);
    acc.z += __shfl_xor(acc.z, 32, 64);
    acc.w += __shfl_xor(acc.w, 32, 64);
    // all 64 lanes finish: each lane handles 2 features (half0 -> f,f+1 ; half1 -> f+2,f+3)
    float di = dinv[i];
    float ax = hf ? acc.z : acc.x;
    float ay = hf ? acc.w : acc.y;
    int off = (i << 7) + fcol + 2 * hf;
    unsigned int rs = *(const unsigned int*)&hs[off];
    float2 sv = __half22float2(*(const __half2*)&rs);
    float2 bv = *(const float2*)&bias[fcol + 2 * hf];
    float r0f = fmaxf(di * (ax + sv.x) + bv.x, 0.f);
    float r1f = fmaxf(di * (ay + sv.y) + bv.y, 0.f);
    __half2 hv = __floats2half2_rn(r0f, r1f);
    *(__half2*)&out[off] = hv;
}

// ---------------- fused gate (MFMA): out = g*o1 + (1-g)*o2. ONE 16-row tile per wave.
__global__ __launch_bounds__(256) void gate_mfma_kernel(const _Float16* __restrict__ o1,
                                                        const _Float16* __restrict__ o2,
                                                        const _Float16* __restrict__ w1,
                                                        const _Float16* __restrict__ w2,
                                                        const float* __restrict__ b,
                                                        float* __restrict__ out32,
                                                        _Float16* __restrict__ out16,
                                                        int write16, int n) {
    __shared__ float trs[4][16 * TRS];
    int tid = threadIdx.x;
    int wv = tid >> 6, lane = tid & 63;
    int m = lane & 15, q = lane >> 4;
    int row0 = blockIdx.x * 64 + wv * 16;
    size_t ar0 = (size_t)min(row0 + m, n - 1) * D;
    fx4 acc[8];
    #pragma unroll
    for (int ct = 0; ct < 8; ct++) acc[ct] = (fx4){0.f, 0.f, 0.f, 0.f};
    #pragma unroll
    for (int ks = 0; ks < 4; ks++) {
        int k0 = ks * 32 + q * 8;
        half8 bf1[8], bf2[8];
        #pragma unroll
        for (int ct = 0; ct < 8; ct++) {
            bf1[ct] = *(const half8*)&w1[(size_t)(ct * 16 + m) * D + k0];
            bf2[ct] = *(const half8*)&w2[(size_t)(ct * 16 + m) * D + k0];
        }
        half8 a10 = *(const half8*)&o1[ar0 + k0];
        half8 a20 = *(const half8*)&o2[ar0 + k0];
        #pragma unroll
        for (int ct = 0; ct < 8; ct++) {
            acc[ct] = __builtin_amdgcn_mfma_f32_16x16x32_f16(a10, bf1[ct], acc[ct], 0, 0, 0);
            acc[ct] = __builtin_amdgcn_mfma_f32_16x16x32_f16(a20, bf2[ct], acc[ct], 0, 0, 0);
        }
    }
    // hoist bias: lane needs b[ks*32+q*8 .. +7] for ks=0..3
    float bb[4][8];
    #pragma unroll
    for (int ks = 0; ks < 4; ks++) {
        float4 b0 = *(const float4*)&b[ks * 32 + q * 8];
        float4 b1 = *(const float4*)&b[ks * 32 + q * 8 + 4];
        bb[ks][0] = b0.x; bb[ks][1] = b0.y; bb[ks][2] = b0.z; bb[ks][3] = b0.w;
        bb[ks][4] = b1.x; bb[ks][5] = b1.y; bb[ks][6] = b1.z; bb[ks][7] = b1.w;
    }
    float* Wl = trs[wv];
    #pragma unroll
    for (int reg = 0; reg < 4; reg++)
        #pragma unroll
        for (int ct = 0; ct < 8; ct++)
            Wl[(q * 4 + reg) * TRS + ct * 16 + m] = acc[ct][reg];
    int r = row0 + m;
    size_t rr = (size_t)min(r, n - 1) * D;
    #pragma unroll
    for (int ks = 0; ks < 4; ks++) {
        int c0 = ks * 32 + q * 8;
        float4 p0 = *(const float4*)&Wl[m * TRS + c0];
        float4 p1 = *(const float4*)&Wl[m * TRS + c0 + 4];
        half8 u1 = *(const half8*)&o1[rr + c0];
        half8 u2 = *(const half8*)&o2[rr + c0];
        float pv[8] = {p0.x, p0.y, p0.z, p0.w, p1.x, p1.y, p1.z, p1.w};
        float res[8];
        #pragma unroll
        for (int j = 0; j < 8; j++) {
            float tv = pv[j] + bb[ks][j];
            float g = 1.0f / (1.0f + __expf(-tv));
            res[j] = g * (float)u1[j] + (1.0f - g) * (float)u2[j];
        }
        if (r < n) {
            if (write16) {
                half8 hv = {(_Float16)res[0], (_Float16)res[1], (_Float16)res[2], (_Float16)res[3],
                            (_Float16)res[4], (_Float16)res[5], (_Float16)res[6], (_Float16)res[7]};
                *(half8*)&out16[rr + c0] = hv;
            } else {
                *(float4*)&out32[rr + c0]     = make_float4(res[0], res[1], res[2], res[3]);
                *(float4*)&out32[rr + c0 + 4] = make_float4(res[4], res[5], res[6], res[7]);
            }
        }
    }
}

// ---------------------------------------------------------------- launch
extern "C" void kernel_launch(void* const* d_in, const int* in_sizes, int n_in,
                              void* d_out, int out_size, void* d_ws, size_t ws_size,
                              hipStream_t stream) {
    const float* x   = (const float*)d_in[0];
    const int*   eix = (const int*)d_in[1];
    const float* W1  = (const float*)d_in[2];
    const float* bc1 = (const float*)d_in[3];
    const float* W2  = (const float*)d_in[4];
    const float* bc2 = (const float*)d_in[5];
    const float* w11 = (const float*)d_in[6];
    const float* w12 = (const float*)d_in[7];
    const float* b1  = (const float*)d_in[8];
    const float* w21 = (const float*)d_in[9];
    const float* w22 = (const float*)d_in[10];
    const float* b2  = (const float*)d_in[11];
    int n = in_sizes[0] / D;
    int e = in_sizes[1] / 2;
    const int* src = eix;
    const int* dst = eix + e;

    int nb = (n + 127) >> BSH;          // 391 buckets
    int nblk = (e + SEG - 1) / SEG;     // 196 edge segments

    char* p = (char*)d_ws;
    auto alloc = [&](size_t bytes) {
        char* q = p;
        p += (bytes + 255) & ~(size_t)255;
        return q;
    };
    int* gcur1 = (int*)alloc((size_t)2 * 512 * sizeof(int));   // zeroed in prep y==6
    int* gcur2 = gcur1 + 512;
    unsigned int* rec1 = (unsigned int*)alloc((size_t)nb * RCAP * sizeof(unsigned int));
    unsigned int* rec2 = (unsigned int*)alloc((size_t)nb * RCAP * sizeof(unsigned int));
    int*   ip1   = (int*)alloc((size_t)n * sizeof(int));
    int*   ipe1  = (int*)alloc((size_t)n * sizeof(int));
    int*   ip2   = (int*)alloc((size_t)n * sizeof(int));
    int*   ipe2  = (int*)alloc((size_t)n * sizeof(int));
    float* dinv1 = (float*)alloc((size_t)(n + 1) * sizeof(float));
    float* dinv2 = (float*)alloc((size_t)(n + 1) * sizeof(float));
    unsigned short* adj1 = (unsigned short*)alloc((size_t)nb * ACAP * sizeof(unsigned short));
    unsigned short* adj2 = (unsigned short*)alloc((size_t)nb * ACAP * sizeof(unsigned short));
    _Float16* W1t  = (_Float16*)alloc((size_t)D * D * sizeof(_Float16));
    _Float16* W2t  = (_Float16*)alloc((size_t)D * D * sizeof(_Float16));
    _Float16* w11h = (_Float16*)alloc((size_t)D * D * sizeof(_Float16));
    _Float16* w12h = (_Float16*)alloc((size_t)D * D * sizeof(_Float16));
    _Float16* w21h = (_Float16*)alloc((size_t)D * D * sizeof(_Float16));
    _Float16* w22h = (_Float16*)alloc((size_t)D * D * sizeof(_Float16));
    _Float16* hs1  = (_Float16*)alloc((size_t)(n + 1) * D * sizeof(_Float16)); // +1 zero sentinel row
    _Float16* hs2  = (_Float16*)alloc((size_t)(n + 1) * D * sizeof(_Float16)); // +1 zero sentinel row
    _Float16* o1h  = (_Float16*)alloc((size_t)n * D * sizeof(_Float16));
    _Float16* o2h  = (_Float16*)alloc((size_t)n * D * sizeof(_Float16));
    _Float16* h2h  = (_Float16*)alloc((size_t)n * D * sizeof(_Float16));
    float* outF  = (float*)d_out;

    prep_kernel<<<dim3(16, 7), 256, 0, stream>>>(W1, W2, w11, w12, w21, w22,
                                                 W1t, W2t, w11h, w12h, w21h, w22h,
                                                 gcur1, hs1, hs2, n);
    scat2_kernel<<<nblk, 512, 0, stream>>>(src, dst, e, nb, gcur1, gcur2, rec1, rec2);
    fin_kernel<<<dim3(nb, 2), 256, 0, stream>>>(rec1, rec2, gcur1, gcur2,
                                                adj1, adj2, ip1, ipe1, ip2, ipe2, dinv1, dinv2, n);

    int gG = (n + 63) / 64;     // 782 blocks (64 rows/block, 16 rows/wave)
    int gA = (n + 3) / 4;       // 4 nodes/block (4 waves)
    // ---- layer 1
    gemm_f32a_kernel<<<gG, 256, 0, stream>>>(x, W1t, dinv1, dinv2, hs1, hs2, n);     // hs1,hs2 (fp16, pre-scaled)
    aggregate2_kernel<<<dim3(gA, 2), 256, 0, stream>>>((const __half*)hs1, (const __half*)hs2,
                                                       ip1, ipe1, adj1, dinv1,
                                                       ip2, ipe2, adj2, dinv2,
                                                       bc1, o1h, o2h, n);            // o1,o2 fp16
    gate_mfma_kernel<<<gG, 256, 0, stream>>>(o1h, o2h, w11h, w12h, b1,
                                             nullptr, h2h, 1, n);                    // h2 fp16
    // ---- layer 2
    gemm_f16a_kernel<<<gG, 256, 0, stream>>>(h2h, W2t, dinv1, dinv2, hs1, hs2, n);   // hh pre-scaled
    aggregate2_kernel<<<dim3(gA, 2), 256, 0, stream>>>((const __half*)hs1, (const __half*)hs2,
                                                       ip1, ipe1, adj1, dinv1,
                                                       ip2, ipe2, adj2, dinv2,
                                                       bc2, o1h, o2h, n);            // p1,p2 fp16
    gate_mfma_kernel<<<gG, 256, 0, stream>>>(o1h, o2h, w21h, w22h, b2, outF, nullptr, 0, n); // out fp32
}

// Round 10
// 315.699 us; speedup vs baseline: 1.1282x; 1.1282x over previous
//
#include <hip/hip_runtime.h>
#include <hip/hip_bf16.h>
#include <hip/hip_fp16.h>
#include <math.h>

#define D 128
#define SEG 4096           // edges per block in scat2 (196 blocks; SEG=1024 measured WORSE, r5)
#define BSH 7              // bucket shift: bucket = node >> 7 (128 nodes/bucket)
#define RCAP 4096          // fixed record capacity per bucket
#define ACAP 4096          // fixed adjacency capacity per bucket (16-padded lists; mean ~3050, max ~3300)
#define TRS 133            // LDS transpose row stride (fp32) -> <=2-way bank aliasing (free)

typedef _Float16 half8  __attribute__((ext_vector_type(8)));
typedef _Float16 half4v __attribute__((ext_vector_type(4)));
typedef float    fx4    __attribute__((ext_vector_type(4)));

// ---------------- CSR pass 1 (r7 best-measured form): fused histogram + reservation + scatter.
// 512 threads; int4 edge loads register-cached across phases.
__global__ __launch_bounds__(512) void scat2_kernel(const int* __restrict__ src,
                                                    const int* __restrict__ dst,
                                                    int e, int nb,
                                                    int* __restrict__ gcur1, int* __restrict__ gcur2,
                                                    unsigned int* __restrict__ rec1,
                                                    unsigned int* __restrict__ rec2) {
    __shared__ int h1[512], h2[512], o1[512], o2[512], run1[512], run2[512];
    int tid = threadIdx.x;
    for (int b = tid; b < nb; b += 512) { h1[b] = 0; h2[b] = 0; run1[b] = 0; run2[b] = 0; }
    __syncthreads();
    int s0 = blockIdx.x * SEG;
    int s1 = min(e, s0 + SEG);
    int4 sv4[2], dv4[2];
    int np[2];                       // valid edges in pack (0,4, or tail count)
    #pragma unroll
    for (int it = 0; it < 2; it++) {
        int idx = s0 + (it * 512 + tid) * 4;
        int nv = 0;
        if (idx + 3 < s1) {
            sv4[it] = *(const int4*)&src[idx];
            dv4[it] = *(const int4*)&dst[idx];
            nv = 4;
        } else if (idx < s1) {       // ragged tail
            nv = s1 - idx;
            int sv[4] = {0,0,0,0}, dv[4] = {0,0,0,0};
            for (int k = 0; k < nv; k++) { sv[k] = src[idx + k]; dv[k] = dst[idx + k]; }
            sv4[it] = make_int4(sv[0], sv[1], sv[2], sv[3]);
            dv4[it] = make_int4(dv[0], dv[1], dv[2], dv[3]);
        }
        np[it] = nv;
        int dvv[4] = {dv4[it].x, dv4[it].y, dv4[it].z, dv4[it].w};
        int svv[4] = {sv4[it].x, sv4[it].y, sv4[it].z, sv4[it].w};
        for (int k = 0; k < nv; k++) {
            atomicAdd(&h1[dvv[k] >> BSH], 1);
            atomicAdd(&h2[svv[k] >> BSH], 1);
        }
    }
    __syncthreads();
    for (int b = tid; b < nb; b += 512) {
        o1[b] = atomicAdd(&gcur1[b], h1[b]);
        o2[b] = atomicAdd(&gcur2[b], h2[b]);
    }
    __syncthreads();
    #pragma unroll
    for (int it = 0; it < 2; it++) {
        int nv = np[it];
        int dvv[4] = {dv4[it].x, dv4[it].y, dv4[it].z, dv4[it].w};
        int svv[4] = {sv4[it].x, sv4[it].y, sv4[it].z, sv4[it].w};
        for (int k = 0; k < nv; k++) {
            unsigned int sv = (unsigned int)svv[k];
            unsigned int dv = (unsigned int)dvv[k];
            int b1 = dv >> BSH, b2 = sv >> BSH;
            int p1 = o1[b1] + atomicAdd(&run1[b1], 1);
            if (p1 < RCAP) rec1[(size_t)b1 * RCAP + p1] = (dv << 16) | sv;
            int p2 = o2[b2] + atomicAdd(&run2[b2], 1);
            if (p2 < RCAP) rec2[(size_t)b2 * RCAP + p2] = (sv << 16) | dv;
        }
    }
}

// ---------------- CSR pass 2: per (bucket,dir) LDS-local CSR, 16-padded lists (for the
// 16-edge/iter aggregate). 256 threads; uint4 loads; single-wave shfl scan.
__global__ __launch_bounds__(256) void fin_kernel(const unsigned int* __restrict__ rec1,
                                                  const unsigned int* __restrict__ rec2,
                                                  const int* __restrict__ gcur1, const int* __restrict__ gcur2,
                                                  unsigned short* __restrict__ adj1, unsigned short* __restrict__ adj2,
                                                  int* __restrict__ ip1, int* __restrict__ ipe1,
                                                  int* __restrict__ ip2, int* __restrict__ ipe2,
                                                  float* __restrict__ dinv1, float* __restrict__ dinv2,
                                                  int n) {
    __shared__ __align__(16) unsigned int Lrec[RCAP];
    __shared__ __align__(16) unsigned short sadj[ACAP];
    __shared__ int deg[128], pscan[128], cur[128];
    __shared__ int ptot_s;
    int bkt = blockIdx.x;
    int dir = blockIdx.y;
    const unsigned int* rec = dir ? rec2 : rec1;
    const int* gc = dir ? gcur2 : gcur1;
    unsigned short* adj = dir ? adj2 : adj1;
    int* ip  = dir ? ip2 : ip1;
    int* ipe = dir ? ipe2 : ipe1;
    float* dinv = dir ? dinv2 : dinv1;

    int tid = threadIdx.x;
    int cnt = gc[bkt];
    if (cnt > RCAP) cnt = RCAP;
    size_t rbase = (size_t)bkt * RCAP;
    if (tid < 128) { deg[tid] = 0; cur[tid] = 0; }
    for (int i = tid * 4; i < cnt; i += 1024) {
        if (i + 3 < cnt) *(uint4*)&Lrec[i] = *(const uint4*)&rec[rbase + i];
        else for (int k = 0; i + k < cnt; k++) Lrec[i + k] = rec[rbase + i + k];
    }
    __syncthreads();
    int base = bkt << BSH;
    for (int i = tid * 4; i < cnt; i += 1024) {
        int lim = min(4, cnt - i);
        for (int k = 0; k < lim; k++)
            atomicAdd(&deg[(int)(Lrec[i + k] >> 16) - base], 1);
    }
    __syncthreads();
    if (tid < 64) {                      // single-wave scan of 128 padded degrees (16-pad)
        int a = (deg[2 * tid] + 15) & ~15;
        int b = (deg[2 * tid + 1] + 15) & ~15;
        int s = a + b;
        #pragma unroll
        for (int off = 1; off < 64; off <<= 1) {
            int u = __shfl_up(s, off, 64);
            if (tid >= off) s += u;
        }
        pscan[2 * tid + 1] = s;
        pscan[2 * tid]     = s - b;
        if (tid == 63) ptot_s = min(s, ACAP);
    }
    __syncthreads();
    int ptot = ptot_s;
    unsigned int nn = ((unsigned int)n << 16) | (unsigned int)n;
    uint4 fillv = make_uint4(nn, nn, nn, nn);
    for (int i = tid * 8; i < ptot; i += 2048) *(uint4*)&sadj[i] = fillv;   // sentinel fill (ptot % 16 == 0)
    __syncthreads();
    for (int i = tid; i < cnt; i += 256) {
        unsigned int r = Lrec[i];
        int l = (int)(r >> 16) - base;
        int pd = (deg[l] + 15) & ~15;
        int pos = pscan[l] - pd + atomicAdd(&cur[l], 1);
        if (pos < ACAP) sadj[pos] = (unsigned short)(r & 0xffffu);
    }
    __syncthreads();
    int gbase = bkt * ACAP;
    for (int i = tid * 8; i < ptot; i += 2048)
        *(uint4*)&adj[gbase + i] = *(const uint4*)&sadj[i];
    if (tid < 128) {
        int node = base + tid;
        if (node < n) {
            int pd = (deg[tid] + 15) & ~15;
            ip[node]  = gbase + pscan[tid] - pd;
            ipe[node] = gbase + pscan[tid];
            dinv[node] = rsqrtf((float)deg[tid] + 1.0f);
        }
    }
}

// ---------------- weight prep (merged): y=0,1 transpose W1/W2 to fp16 [c][k];
// y=2..5 fp16-convert gates; y=6 zero work (gcur, hs sentinel rows).
__global__ __launch_bounds__(256) void prep_kernel(const float* __restrict__ W1, const float* __restrict__ W2,
                                                   const float* __restrict__ w11, const float* __restrict__ w12,
                                                   const float* __restrict__ w21, const float* __restrict__ w22,
                                                   _Float16* __restrict__ T1, _Float16* __restrict__ T2,
                                                   _Float16* __restrict__ o11, _Float16* __restrict__ o12,
                                                   _Float16* __restrict__ o21, _Float16* __restrict__ o22,
                                                   int* __restrict__ gcur, _Float16* __restrict__ hs1,
                                                   _Float16* __restrict__ hs2, int n) {
    __shared__ float s[32][33];
    int which = blockIdx.y;
    if (which < 2) {
        const float* w = which ? W2 : W1;
        _Float16* t = which ? T2 : T1;
        int tk = (blockIdx.x >> 2) * 32;
        int tc = (blockIdx.x & 3) * 32;
        int lr = threadIdx.x >> 5;
        int lc = threadIdx.x & 31;
        #pragma unroll
        for (int i = 0; i < 32; i += 8)
            s[lr + i][lc] = w[(size_t)(tk + lr + i) * D + tc + lc];
        __syncthreads();
        #pragma unroll
        for (int i = 0; i < 32; i += 8)
            t[(size_t)(tc + lr + i) * D + tk + lc] = (_Float16)s[lc][lr + i];
    } else if (which < 6) {
        int wsel = which - 2;
        const float* w = (wsel == 0) ? w11 : (wsel == 1) ? w12 : (wsel == 2) ? w21 : w22;
        _Float16* o = (wsel == 0) ? o11 : (wsel == 1) ? o12 : (wsel == 2) ? o21 : o22;
        int idx = (blockIdx.x * 256 + threadIdx.x) * 4;
        float4 v = *(const float4*)&w[idx];
        half4v h = {(_Float16)v.x, (_Float16)v.y, (_Float16)v.z, (_Float16)v.w};
        *(half4v*)&o[idx] = h;
    } else {
        int tid = threadIdx.x;
        if (blockIdx.x == 0) {
            #pragma unroll
            for (int k = 0; k < 4; k++) gcur[tid + k * 256] = 0;       // 1024 ints
        } else if (blockIdx.x == 1) {
            if (tid < 128) hs1[(size_t)n * D + tid] = (_Float16)0.f;   // sentinel row
        } else if (blockIdx.x == 2) {
            if (tid < 128) hs2[(size_t)n * D + tid] = (_Float16)0.f;
        }
    }
}

// ------------------------------------------------- MFMA GEMM, fp32 A (r7 form: 2 row-tiles/wave).
// Epilogue writes TWO pre-scaled fp16 copies: hs1 = dinv1[r]*row, hs2 = dinv2[r]*row.
__global__ __launch_bounds__(256) void gemm_f32a_kernel(const float* __restrict__ A,
                                                        const _Float16* __restrict__ Wt,
                                                        const float* __restrict__ dinv1,
                                                        const float* __restrict__ dinv2,
                                                        _Float16* __restrict__ hs1,
                                                        _Float16* __restrict__ hs2, int n) {
    __shared__ float trs[4][16 * TRS];
    int tid = threadIdx.x;
    int wv = tid >> 6, lane = tid & 63;
    int m = lane & 15, q = lane >> 4;
    int row0 = blockIdx.x * 128 + wv * 32;
    size_t ar0 = (size_t)min(row0 + m, n - 1) * D;
    size_t ar1 = (size_t)min(row0 + 16 + m, n - 1) * D;
    fx4 acc[2][8];
    #pragma unroll
    for (int t = 0; t < 2; t++)
        #pragma unroll
        for (int ct = 0; ct < 8; ct++) acc[t][ct] = (fx4){0.f, 0.f, 0.f, 0.f};
    #pragma unroll
    for (int ks = 0; ks < 4; ks++) {
        int k0 = ks * 32 + q * 8;
        half8 bf[8];
        #pragma unroll
        for (int ct = 0; ct < 8; ct++)
            bf[ct] = *(const half8*)&Wt[(size_t)(ct * 16 + m) * D + k0];
        float4 u0 = *(const float4*)&A[ar0 + k0];
        float4 u1 = *(const float4*)&A[ar0 + k0 + 4];
        half8 a0 = {(_Float16)u0.x, (_Float16)u0.y, (_Float16)u0.z, (_Float16)u0.w,
                    (_Float16)u1.x, (_Float16)u1.y, (_Float16)u1.z, (_Float16)u1.w};
        float4 v0 = *(const float4*)&A[ar1 + k0];
        float4 v1 = *(const float4*)&A[ar1 + k0 + 4];
        half8 a1 = {(_Float16)v0.x, (_Float16)v0.y, (_Float16)v0.z, (_Float16)v0.w,
                    (_Float16)v1.x, (_Float16)v1.y, (_Float16)v1.z, (_Float16)v1.w};
        #pragma unroll
        for (int ct = 0; ct < 8; ct++) {
            acc[0][ct] = __builtin_amdgcn_mfma_f32_16x16x32_f16(a0, bf[ct], acc[0][ct], 0, 0, 0);
            acc[1][ct] = __builtin_amdgcn_mfma_f32_16x16x32_f16(a1, bf[ct], acc[1][ct], 0, 0, 0);
        }
    }
    float* Wl = trs[wv];
    #pragma unroll
    for (int t = 0; t < 2; t++) {
        #pragma unroll
        for (int reg = 0; reg < 4; reg++)
            #pragma unroll
            for (int ct = 0; ct < 8; ct++)
                Wl[(q * 4 + reg) * TRS + ct * 16 + m] = acc[t][ct][reg];
        int r = row0 + t * 16 + m;
        if (r < n) {
            float s1 = dinv1[r], s2 = dinv2[r];
            size_t rr = (size_t)r * D;
            #pragma unroll
            for (int ks = 0; ks < 4; ks++) {
                int c0 = ks * 32 + q * 8;
                float4 p0 = *(const float4*)&Wl[m * TRS + c0];
                float4 p1 = *(const float4*)&Wl[m * TRS + c0 + 4];
                float pv[8] = {p0.x, p0.y, p0.z, p0.w, p1.x, p1.y, p1.z, p1.w};
                half8 h1v, h2v;
                #pragma unroll
                for (int j = 0; j < 8; j++) {
                    h1v[j] = (_Float16)(s1 * pv[j]);
                    h2v[j] = (_Float16)(s2 * pv[j]);
                }
                *(half8*)&hs1[rr + c0] = h1v;
                *(half8*)&hs2[rr + c0] = h2v;
            }
        }
    }
}

// ------------------------------------------------- MFMA GEMM, fp16 A (r7 form)
__global__ __launch_bounds__(256) void gemm_f16a_kernel(const _Float16* __restrict__ A,
                                                        const _Float16* __restrict__ Wt,
                                                        const float* __restrict__ dinv1,
                                                        const float* __restrict__ dinv2,
                                                        _Float16* __restrict__ hs1,
                                                        _Float16* __restrict__ hs2, int n) {
    __shared__ float trs[4][16 * TRS];
    int tid = threadIdx.x;
    int wv = tid >> 6, lane = tid & 63;
    int m = lane & 15, q = lane >> 4;
    int row0 = blockIdx.x * 128 + wv * 32;
    size_t ar0 = (size_t)min(row0 + m, n - 1) * D;
    size_t ar1 = (size_t)min(row0 + 16 + m, n - 1) * D;
    fx4 acc[2][8];
    #pragma unroll
    for (int t = 0; t < 2; t++)
        #pragma unroll
        for (int ct = 0; ct < 8; ct++) acc[t][ct] = (fx4){0.f, 0.f, 0.f, 0.f};
    #pragma unroll
    for (int ks = 0; ks < 4; ks++) {
        int k0 = ks * 32 + q * 8;
        half8 bf[8];
        #pragma unroll
        for (int ct = 0; ct < 8; ct++)
            bf[ct] = *(const half8*)&Wt[(size_t)(ct * 16 + m) * D + k0];
        half8 a0 = *(const half8*)&A[ar0 + k0];
        half8 a1 = *(const half8*)&A[ar1 + k0];
        #pragma unroll
        for (int ct = 0; ct < 8; ct++) {
            acc[0][ct] = __builtin_amdgcn_mfma_f32_16x16x32_f16(a0, bf[ct], acc[0][ct], 0, 0, 0);
            acc[1][ct] = __builtin_amdgcn_mfma_f32_16x16x32_f16(a1, bf[ct], acc[1][ct], 0, 0, 0);
        }
    }
    float* Wl = trs[wv];
    #pragma unroll
    for (int t = 0; t < 2; t++) {
        #pragma unroll
        for (int reg = 0; reg < 4; reg++)
            #pragma unroll
            for (int ct = 0; ct < 8; ct++)
                Wl[(q * 4 + reg) * TRS + ct * 16 + m] = acc[t][ct][reg];
        int r = row0 + t * 16 + m;
        if (r < n) {
            float s1 = dinv1[r], s2 = dinv2[r];
            size_t rr = (size_t)r * D;
            #pragma unroll
            for (int ks = 0; ks < 4; ks++) {
                int c0 = ks * 32 + q * 8;
                float4 p0 = *(const float4*)&Wl[m * TRS + c0];
                float4 p1 = *(const float4*)&Wl[m * TRS + c0 + 4];
                float pv[8] = {p0.x, p0.y, p0.z, p0.w, p1.x, p1.y, p1.z, p1.w};
                half8 h1v, h2v;
                #pragma unroll
                for (int j = 0; j < 8; j++) {
                    h1v[j] = (_Float16)(s1 * pv[j]);
                    h2v[j] = (_Float16)(s2 * pv[j]);
                }
                *(half8*)&hs1[rr + c0] = h1v;
                *(half8*)&hs2[rr + c0] = h2v;
            }
        }
    }
}

// ---------------------------------------- aggregation: 16 edges/iter (8 gathers per
// half-wave in flight — doubles per-wave MLP vs the 8-edge form whose VGPR=16 showed
// only ~4 outstanding gathers). Lists are 16-padded; sentinel id=n has hs[n]=0.
__global__ __launch_bounds__(256) void aggregate2_kernel(const __half* __restrict__ hs1g,
                                                         const __half* __restrict__ hs2g,
                                                         const int* __restrict__ ip1,
                                                         const int* __restrict__ ipe1,
                                                         const unsigned short* __restrict__ adj1,
                                                         const float* __restrict__ dinv1,
                                                         const int* __restrict__ ip2,
                                                         const int* __restrict__ ipe2,
                                                         const unsigned short* __restrict__ adj2,
                                                         const float* __restrict__ dinv2,
                                                         const float* __restrict__ bias,
                                                         _Float16* __restrict__ out1,
                                                         _Float16* __restrict__ out2, int n) {
    const __half* hs = blockIdx.y ? hs2g : hs1g;
    const int* ip  = blockIdx.y ? ip2 : ip1;
    const int* ipe = blockIdx.y ? ipe2 : ipe1;
    const unsigned short* adj = blockIdx.y ? adj2 : adj1;
    const float* dinv = blockIdx.y ? dinv2 : dinv1;
    _Float16* out = blockIdx.y ? out2 : out1;
    int wid = threadIdx.x >> 6, lane = threadIdx.x & 63;
    int hf = lane >> 5, l32 = lane & 31;
    int i = blockIdx.x * 4 + wid;
    if (i >= n) return;
    int beg = ip[i], endp = ipe[i];
    int fcol = 4 * l32;
    float4 acc = make_float4(0.f, 0.f, 0.f, 0.f);
    if (beg < endp) {
        int hoff = hf << 3;                 // half 0 -> entries j..j+7, half 1 -> j+8..j+15
        int j = beg;
        uint4 iv = *(const uint4*)&adj[j + hoff];
        while (true) {
            int jn = j + 16;
            int jp = jn < endp ? jn : j;    // clamp: last iter re-loads current (independent)
            uint4 niv = *(const uint4*)&adj[jp + hoff];
            int s0 = iv.x & 0xffff, s1 = iv.x >> 16;
            int s2 = iv.y & 0xffff, s3 = iv.y >> 16;
            int s4 = iv.z & 0xffff, s5 = iv.z >> 16;
            int s6 = iv.w & 0xffff, s7 = iv.w >> 16;
            uint2 r0 = *(const uint2*)&hs[(s0 << 7) + fcol];
            uint2 r1 = *(const uint2*)&hs[(s1 << 7) + fcol];
            uint2 r2 = *(const uint2*)&hs[(s2 << 7) + fcol];
            uint2 r3 = *(const uint2*)&hs[(s3 << 7) + fcol];
            uint2 r4 = *(const uint2*)&hs[(s4 << 7) + fcol];
            uint2 r5 = *(const uint2*)&hs[(s5 << 7) + fcol];
            uint2 r6 = *(const uint2*)&hs[(s6 << 7) + fcol];
            uint2 r7 = *(const uint2*)&hs[(s7 << 7) + fcol];
            float2 a0 = __half22float2(*(__half2*)&r0.x), b0 = __half22float2(*(__half2*)&r0.y);
            float2 a1 = __half22float2(*(__half2*)&r1.x), b1 = __half22float2(*(__half2*)&r1.y);
            float2 a2 = __half22float2(*(__half2*)&r2.x), b2 = __half22float2(*(__half2*)&r2.y);
            float2 a3 = __half22float2(*(__half2*)&r3.x), b3 = __half22float2(*(__half2*)&r3.y);
            float2 a4 = __half22float2(*(__half2*)&r4.x), b4 = __half22float2(*(__half2*)&r4.y);
            float2 a5 = __half22float2(*(__half2*)&r5.x), b5 = __half22float2(*(__half2*)&r5.y);
            float2 a6 = __half22float2(*(__half2*)&r6.x), b6 = __half22float2(*(__half2*)&r6.y);
            float2 a7 = __half22float2(*(__half2*)&r7.x), b7 = __half22float2(*(__half2*)&r7.y);
            acc.x += (a0.x + a1.x + a2.x + a3.x) + (a4.x + a5.x + a6.x + a7.x);
            acc.y += (a0.y + a1.y + a2.y + a3.y) + (a4.y + a5.y + a6.y + a7.y);
            acc.z += (b0.x + b1.x + b2.x + b3.x) + (b4.x + b5.x + b6.x + b7.x);
            acc.w += (b0.y + b1.y + b2.y + b3.y) + (b4.y + b5.y + b6.y + b7.y);
            if (jn >= endp) break;
            iv = niv; j = jn;
        }
    }
    acc.x += __shfl_xor(acc.x, 32, 64);
    acc.y += __shfl_xor(acc.y, 32, 64);
    acc.z += __shfl_xor(acc.z, 32, 64);
    acc.w += __shfl_xor(acc.w, 32, 64);
    // all 64 lanes finish: each lane handles 2 features (half0 -> f,f+1 ; half1 -> f+2,f+3)
    float di = dinv[i];
    float ax = hf ? acc.z : acc.x;
    float ay = hf ? acc.w : acc.y;
    int off = (i << 7) + fcol + 2 * hf;
    unsigned int rs = *(const unsigned int*)&hs[off];
    float2 sv = __half22float2(*(const __half2*)&rs);
    float2 bv = *(const float2*)&bias[fcol + 2 * hf];
    float r0f = fmaxf(di * (ax + sv.x) + bv.x, 0.f);
    float r1f = fmaxf(di * (ay + sv.y) + bv.y, 0.f);
    __half2 hv = __floats2half2_rn(r0f, r1f);
    *(__half2*)&out[off] = hv;
}

// ---------------- fused gate (MFMA, r7 form): out = g*o1 + (1-g)*o2
__global__ __launch_bounds__(256) void gate_mfma_kernel(const _Float16* __restrict__ o1,
                                                        const _Float16* __restrict__ o2,
                                                        const _Float16* __restrict__ w1,
                                                        const _Float16* __restrict__ w2,
                                                        const float* __restrict__ b,
                                                        float* __restrict__ out32,
                                                        _Float16* __restrict__ out16,
                                                        int write16, int n) {
    __shared__ float trs[4][16 * TRS];
    int tid = threadIdx.x;
    int wv = tid >> 6, lane = tid & 63;
    int m = lane & 15, q = lane >> 4;
    int row0 = blockIdx.x * 128 + wv * 32;
    size_t ar0 = (size_t)min(row0 + m, n - 1) * D;
    size_t ar1 = (size_t)min(row0 + 16 + m, n - 1) * D;
    fx4 acc[2][8];
    #pragma unroll
    for (int t = 0; t < 2; t++)
        #pragma unroll
        for (int ct = 0; ct < 8; ct++) acc[t][ct] = (fx4){0.f, 0.f, 0.f, 0.f};
    #pragma unroll
    for (int ks = 0; ks < 4; ks++) {
        int k0 = ks * 32 + q * 8;
        half8 bf1[8], bf2[8];
        #pragma unroll
        for (int ct = 0; ct < 8; ct++) {
            bf1[ct] = *(const half8*)&w1[(size_t)(ct * 16 + m) * D + k0];
            bf2[ct] = *(const half8*)&w2[(size_t)(ct * 16 + m) * D + k0];
        }
        half8 a10 = *(const half8*)&o1[ar0 + k0];
        half8 a20 = *(const half8*)&o2[ar0 + k0];
        half8 a11 = *(const half8*)&o1[ar1 + k0];
        half8 a21 = *(const half8*)&o2[ar1 + k0];
        #pragma unroll
        for (int ct = 0; ct < 8; ct++) {
            acc[0][ct] = __builtin_amdgcn_mfma_f32_16x16x32_f16(a10, bf1[ct], acc[0][ct], 0, 0, 0);
            acc[0][ct] = __builtin_amdgcn_mfma_f32_16x16x32_f16(a20, bf2[ct], acc[0][ct], 0, 0, 0);
            acc[1][ct] = __builtin_amdgcn_mfma_f32_16x16x32_f16(a11, bf1[ct], acc[1][ct], 0, 0, 0);
            acc[1][ct] = __builtin_amdgcn_mfma_f32_16x16x32_f16(a21, bf2[ct], acc[1][ct], 0, 0, 0);
        }
    }
    // hoist bias: lane needs b[ks*32+q*8 .. +7] for ks=0..3
    float bb[4][8];
    #pragma unroll
    for (int ks = 0; ks < 4; ks++) {
        float4 b0 = *(const float4*)&b[ks * 32 + q * 8];
        float4 b1 = *(const float4*)&b[ks * 32 + q * 8 + 4];
        bb[ks][0] = b0.x; bb[ks][1] = b0.y; bb[ks][2] = b0.z; bb[ks][3] = b0.w;
        bb[ks][4] = b1.x; bb[ks][5] = b1.y; bb[ks][6] = b1.z; bb[ks][7] = b1.w;
    }
    float* Wl = trs[wv];
    #pragma unroll
    for (int t = 0; t < 2; t++) {
        #pragma unroll
        for (int reg = 0; reg < 4; reg++)
            #pragma unroll
            for (int ct = 0; ct < 8; ct++)
                Wl[(q * 4 + reg) * TRS + ct * 16 + m] = acc[t][ct][reg];
        int r = row0 + t * 16 + m;
        size_t rr = (size_t)min(r, n - 1) * D;
        #pragma unroll
        for (int ks = 0; ks < 4; ks++) {
            int c0 = ks * 32 + q * 8;
            float4 p0 = *(const float4*)&Wl[m * TRS + c0];
            float4 p1 = *(const float4*)&Wl[m * TRS + c0 + 4];
            half8 u1 = *(const half8*)&o1[rr + c0];
            half8 u2 = *(const half8*)&o2[rr + c0];
            float pv[8] = {p0.x, p0.y, p0.z, p0.w, p1.x, p1.y, p1.z, p1.w};
            float res[8];
            #pragma unroll
            for (int j = 0; j < 8; j++) {
                float tv = pv[j] + bb[ks][j];
                float g = 1.0f / (1.0f + __expf(-tv));
                res[j] = g * (float)u1[j] + (1.0f - g) * (float)u2[j];
            }
            if (r < n) {
                if (write16) {
                    half8 hv = {(_Float16)res[0], (_Float16)res[1], (_Float16)res[2], (_Float16)res[3],
                                (_Float16)res[4], (_Float16)res[5], (_Float16)res[6], (_Float16)res[7]};
                    *(half8*)&out16[rr + c0] = hv;
                } else {
                    *(float4*)&out32[rr + c0]     = make_float4(res[0], res[1], res[2], res[3]);
                    *(float4*)&out32[rr + c0 + 4] = make_float4(res[4], res[5], res[6], res[7]);
                }
            }
        }
    }
}

// ---------------------------------------------------------------- launch
extern "C" void kernel_launch(void* const* d_in, const int* in_sizes, int n_in,
                              void* d_out, int out_size, void* d_ws, size_t ws_size,
                              hipStream_t stream) {
    const float* x   = (const float*)d_in[0];
    const int*   eix = (const int*)d_in[1];
    const float* W1  = (const float*)d_in[2];
    const float* bc1 = (const float*)d_in[3];
    const float* W2  = (const float*)d_in[4];
    const float* bc2 = (const float*)d_in[5];
    const float* w11 = (const float*)d_in[6];
    const float* w12 = (const float*)d_in[7];
    const float* b1  = (const float*)d_in[8];
    const float* w21 = (const float*)d_in[9];
    const float* w22 = (const float*)d_in[10];
    const float* b2  = (const float*)d_in[11];
    int n = in_sizes[0] / D;
    int e = in_sizes[1] / 2;
    const int* src = eix;
    const int* dst = eix + e;

    int nb = (n + 127) >> BSH;          // 391 buckets
    int nblk = (e + SEG - 1) / SEG;     // 196 edge segments

    char* p = (char*)d_ws;
    auto alloc = [&](size_t bytes) {
        char* q = p;
        p += (bytes + 255) & ~(size_t)255;
        return q;
    };
    int* gcur1 = (int*)alloc((size_t)2 * 512 * sizeof(int));   // zeroed in prep y==6
    int* gcur2 = gcur1 + 512;
    unsigned int* rec1 = (unsigned int*)alloc((size_t)nb * RCAP * sizeof(unsigned int));
    unsigned int* rec2 = (unsigned int*)alloc((size_t)nb * RCAP * sizeof(unsigned int));
    int*   ip1   = (int*)alloc((size_t)n * sizeof(int));
    int*   ipe1  = (int*)alloc((size_t)n * sizeof(int));
    int*   ip2   = (int*)alloc((size_t)n * sizeof(int));
    int*   ipe2  = (int*)alloc((size_t)n * sizeof(int));
    float* dinv1 = (float*)alloc((size_t)(n + 1) * sizeof(float));
    float* dinv2 = (float*)alloc((size_t)(n + 1) * sizeof(float));
    unsigned short* adj1 = (unsigned short*)alloc((size_t)nb * ACAP * sizeof(unsigned short));
    unsigned short* adj2 = (unsigned short*)alloc((size_t)nb * ACAP * sizeof(unsigned short));
    _Float16* W1t  = (_Float16*)alloc((size_t)D * D * sizeof(_Float16));
    _Float16* W2t  = (_Float16*)alloc((size_t)D * D * sizeof(_Float16));
    _Float16* w11h = (_Float16*)alloc((size_t)D * D * sizeof(_Float16));
    _Float16* w12h = (_Float16*)alloc((size_t)D * D * sizeof(_Float16));
    _Float16* w21h = (_Float16*)alloc((size_t)D * D * sizeof(_Float16));
    _Float16* w22h = (_Float16*)alloc((size_t)D * D * sizeof(_Float16));
    _Float16* hs1  = (_Float16*)alloc((size_t)(n + 1) * D * sizeof(_Float16)); // +1 zero sentinel row
    _Float16* hs2  = (_Float16*)alloc((size_t)(n + 1) * D * sizeof(_Float16)); // +1 zero sentinel row
    _Float16* o1h  = (_Float16*)alloc((size_t)n * D * sizeof(_Float16));
    _Float16* o2h  = (_Float16*)alloc((size_t)n * D * sizeof(_Float16));
    _Float16* h2h  = (_Float16*)alloc((size_t)n * D * sizeof(_Float16));
    float* outF  = (float*)d_out;

    prep_kernel<<<dim3(16, 7), 256, 0, stream>>>(W1, W2, w11, w12, w21, w22,
                                                 W1t, W2t, w11h, w12h, w21h, w22h,
                                                 gcur1, hs1, hs2, n);
    scat2_kernel<<<nblk, 512, 0, stream>>>(src, dst, e, nb, gcur1, gcur2, rec1, rec2);
    fin_kernel<<<dim3(nb, 2), 256, 0, stream>>>(rec1, rec2, gcur1, gcur2,
                                                adj1, adj2, ip1, ipe1, ip2, ipe2, dinv1, dinv2, n);

    int gG = (n + 127) / 128;   // 391 blocks (128 rows/block, r7 geometry)
    int gA = (n + 3) / 4;       // 4 nodes/block (4 waves)
    // ---- layer 1
    gemm_f32a_kernel<<<gG, 256, 0, stream>>>(x, W1t, dinv1, dinv2, hs1, hs2, n);     // hs1,hs2 (fp16, pre-scaled)
    aggregate2_kernel<<<dim3(gA, 2), 256, 0, stream>>>((const __half*)hs1, (const __half*)hs2,
                                                       ip1, ipe1, adj1, dinv1,
                                                       ip2, ipe2, adj2, dinv2,
                                                       bc1, o1h, o2h, n);            // o1,o2 fp16
    gate_mfma_kernel<<<gG, 256, 0, stream>>>(o1h, o2h, w11h, w12h, b1,
                                             nullptr, h2h, 1, n);                    // h2 fp16
    // ---- layer 2
    gemm_f16a_kernel<<<gG, 256, 0, stream>>>(h2h, W2t, dinv1, dinv2, hs1, hs2, n);   // hh pre-scaled
    aggregate2_kernel<<<dim3(gA, 2), 256, 0, stream>>>((const __half*)hs1, (const __half*)hs2,
                                                       ip1, ipe1, adj1, dinv1,
                                                       ip2, ipe2, adj2, dinv2,
                                                       bc2, o1h, o2h, n);            // p1,p2 fp16
    gate_mfma_kernel<<<gG, 256, 0, stream>>>(o1h, o2h, w21h, w22h, b2, outF, nullptr, 0, n); // out fp32
}

// Round 11
// 314.132 us; speedup vs baseline: 1.1338x; 1.0050x over previous
//
#include <hip/hip_runtime.h>
#include <hip/hip_bf16.h>
#include <hip/hip_fp16.h>
#include <math.h>

#define D 128
#define SEG 4096           // edges per block in scat2 (196 blocks; SEG=1024 measured WORSE, r5)
#define BSH 7              // bucket shift: bucket = node >> 7 (128 nodes/bucket)
#define RCAP 4096          // fixed record capacity per bucket
#define ACAP 4096          // fixed adjacency capacity per bucket (16-padded lists; mean ~3050, max ~3300)
#define TRS 133            // LDS transpose row stride (fp32) -> <=2-way bank aliasing (free)

typedef _Float16 half8  __attribute__((ext_vector_type(8)));
typedef _Float16 half4v __attribute__((ext_vector_type(4)));
typedef float    fx4    __attribute__((ext_vector_type(4)));

// ---------------- CSR pass 1 (r7 best-measured form): fused histogram + reservation + scatter.
__global__ __launch_bounds__(512) void scat2_kernel(const int* __restrict__ src,
                                                    const int* __restrict__ dst,
                                                    int e, int nb,
                                                    int* __restrict__ gcur1, int* __restrict__ gcur2,
                                                    unsigned int* __restrict__ rec1,
                                                    unsigned int* __restrict__ rec2) {
    __shared__ int h1[512], h2[512], o1[512], o2[512], run1[512], run2[512];
    int tid = threadIdx.x;
    for (int b = tid; b < nb; b += 512) { h1[b] = 0; h2[b] = 0; run1[b] = 0; run2[b] = 0; }
    __syncthreads();
    int s0 = blockIdx.x * SEG;
    int s1 = min(e, s0 + SEG);
    int4 sv4[2], dv4[2];
    int np[2];                       // valid edges in pack (0,4, or tail count)
    #pragma unroll
    for (int it = 0; it < 2; it++) {
        int idx = s0 + (it * 512 + tid) * 4;
        int nv = 0;
        if (idx + 3 < s1) {
            sv4[it] = *(const int4*)&src[idx];
            dv4[it] = *(const int4*)&dst[idx];
            nv = 4;
        } else if (idx < s1) {       // ragged tail
            nv = s1 - idx;
            int sv[4] = {0,0,0,0}, dv[4] = {0,0,0,0};
            for (int k = 0; k < nv; k++) { sv[k] = src[idx + k]; dv[k] = dst[idx + k]; }
            sv4[it] = make_int4(sv[0], sv[1], sv[2], sv[3]);
            dv4[it] = make_int4(dv[0], dv[1], dv[2], dv[3]);
        }
        np[it] = nv;
        int dvv[4] = {dv4[it].x, dv4[it].y, dv4[it].z, dv4[it].w};
        int svv[4] = {sv4[it].x, sv4[it].y, sv4[it].z, sv4[it].w};
        for (int k = 0; k < nv; k++) {
            atomicAdd(&h1[dvv[k] >> BSH], 1);
            atomicAdd(&h2[svv[k] >> BSH], 1);
        }
    }
    __syncthreads();
    for (int b = tid; b < nb; b += 512) {
        o1[b] = atomicAdd(&gcur1[b], h1[b]);
        o2[b] = atomicAdd(&gcur2[b], h2[b]);
    }
    __syncthreads();
    #pragma unroll
    for (int it = 0; it < 2; it++) {
        int nv = np[it];
        int dvv[4] = {dv4[it].x, dv4[it].y, dv4[it].z, dv4[it].w};
        int svv[4] = {sv4[it].x, sv4[it].y, sv4[it].z, sv4[it].w};
        for (int k = 0; k < nv; k++) {
            unsigned int sv = (unsigned int)svv[k];
            unsigned int dv = (unsigned int)dvv[k];
            int b1 = dv >> BSH, b2 = sv >> BSH;
            int p1 = o1[b1] + atomicAdd(&run1[b1], 1);
            if (p1 < RCAP) rec1[(size_t)b1 * RCAP + p1] = (dv << 16) | sv;
            int p2 = o2[b2] + atomicAdd(&run2[b2], 1);
            if (p2 < RCAP) rec2[(size_t)b2 * RCAP + p2] = (sv << 16) | dv;
        }
    }
}

// ---------------- CSR pass 2 (r10 form): per (bucket,dir) LDS-local CSR, 16-padded lists.
__global__ __launch_bounds__(256) void fin_kernel(const unsigned int* __restrict__ rec1,
                                                  const unsigned int* __restrict__ rec2,
                                                  const int* __restrict__ gcur1, const int* __restrict__ gcur2,
                                                  unsigned short* __restrict__ adj1, unsigned short* __restrict__ adj2,
                                                  int* __restrict__ ip1, int* __restrict__ ipe1,
                                                  int* __restrict__ ip2, int* __restrict__ ipe2,
                                                  float* __restrict__ dinv1, float* __restrict__ dinv2,
                                                  int n) {
    __shared__ __align__(16) unsigned int Lrec[RCAP];
    __shared__ __align__(16) unsigned short sadj[ACAP];
    __shared__ int deg[128], pscan[128], cur[128];
    __shared__ int ptot_s;
    int bkt = blockIdx.x;
    int dir = blockIdx.y;
    const unsigned int* rec = dir ? rec2 : rec1;
    const int* gc = dir ? gcur2 : gcur1;
    unsigned short* adj = dir ? adj2 : adj1;
    int* ip  = dir ? ip2 : ip1;
    int* ipe = dir ? ipe2 : ipe1;
    float* dinv = dir ? dinv2 : dinv1;

    int tid = threadIdx.x;
    int cnt = gc[bkt];
    if (cnt > RCAP) cnt = RCAP;
    size_t rbase = (size_t)bkt * RCAP;
    if (tid < 128) { deg[tid] = 0; cur[tid] = 0; }
    for (int i = tid * 4; i < cnt; i += 1024) {
        if (i + 3 < cnt) *(uint4*)&Lrec[i] = *(const uint4*)&rec[rbase + i];
        else for (int k = 0; i + k < cnt; k++) Lrec[i + k] = rec[rbase + i + k];
    }
    __syncthreads();
    int base = bkt << BSH;
    for (int i = tid * 4; i < cnt; i += 1024) {
        int lim = min(4, cnt - i);
        for (int k = 0; k < lim; k++)
            atomicAdd(&deg[(int)(Lrec[i + k] >> 16) - base], 1);
    }
    __syncthreads();
    if (tid < 64) {                      // single-wave scan of 128 padded degrees (16-pad)
        int a = (deg[2 * tid] + 15) & ~15;
        int b = (deg[2 * tid + 1] + 15) & ~15;
        int s = a + b;
        #pragma unroll
        for (int off = 1; off < 64; off <<= 1) {
            int u = __shfl_up(s, off, 64);
            if (tid >= off) s += u;
        }
        pscan[2 * tid + 1] = s;
        pscan[2 * tid]     = s - b;
        if (tid == 63) ptot_s = min(s, ACAP);
    }
    __syncthreads();
    int ptot = ptot_s;
    unsigned int nn = ((unsigned int)n << 16) | (unsigned int)n;
    uint4 fillv = make_uint4(nn, nn, nn, nn);
    for (int i = tid * 8; i < ptot; i += 2048) *(uint4*)&sadj[i] = fillv;   // sentinel fill (ptot % 16 == 0)
    __syncthreads();
    for (int i = tid; i < cnt; i += 256) {
        unsigned int r = Lrec[i];
        int l = (int)(r >> 16) - base;
        int pd = (deg[l] + 15) & ~15;
        int pos = pscan[l] - pd + atomicAdd(&cur[l], 1);
        if (pos < ACAP) sadj[pos] = (unsigned short)(r & 0xffffu);
    }
    __syncthreads();
    int gbase = bkt * ACAP;
    for (int i = tid * 8; i < ptot; i += 2048)
        *(uint4*)&adj[gbase + i] = *(const uint4*)&sadj[i];
    if (tid < 128) {
        int node = base + tid;
        if (node < n) {
            int pd = (deg[tid] + 15) & ~15;
            ip[node]  = gbase + pscan[tid] - pd;
            ipe[node] = gbase + pscan[tid];
            dinv[node] = rsqrtf((float)deg[tid] + 1.0f);
        }
    }
}

// ---------------- weight prep (merged): y=0,1 transpose W1/W2 to fp16 [c][k];
// y=2..5 fp16-convert gates; y=6 zero work (gcur, hs sentinel rows).
__global__ __launch_bounds__(256) void prep_kernel(const float* __restrict__ W1, const float* __restrict__ W2,
                                                   const float* __restrict__ w11, const float* __restrict__ w12,
                                                   const float* __restrict__ w21, const float* __restrict__ w22,
                                                   _Float16* __restrict__ T1, _Float16* __restrict__ T2,
                                                   _Float16* __restrict__ o11, _Float16* __restrict__ o12,
                                                   _Float16* __restrict__ o21, _Float16* __restrict__ o22,
                                                   int* __restrict__ gcur, _Float16* __restrict__ hs1,
                                                   _Float16* __restrict__ hs2, int n) {
    __shared__ float s[32][33];
    int which = blockIdx.y;
    if (which < 2) {
        const float* w = which ? W2 : W1;
        _Float16* t = which ? T2 : T1;
        int tk = (blockIdx.x >> 2) * 32;
        int tc = (blockIdx.x & 3) * 32;
        int lr = threadIdx.x >> 5;
        int lc = threadIdx.x & 31;
        #pragma unroll
        for (int i = 0; i < 32; i += 8)
            s[lr + i][lc] = w[(size_t)(tk + lr + i) * D + tc + lc];
        __syncthreads();
        #pragma unroll
        for (int i = 0; i < 32; i += 8)
            t[(size_t)(tc + lr + i) * D + tk + lc] = (_Float16)s[lc][lr + i];
    } else if (which < 6) {
        int wsel = which - 2;
        const float* w = (wsel == 0) ? w11 : (wsel == 1) ? w12 : (wsel == 2) ? w21 : w22;
        _Float16* o = (wsel == 0) ? o11 : (wsel == 1) ? o12 : (wsel == 2) ? o21 : o22;
        int idx = (blockIdx.x * 256 + threadIdx.x) * 4;
        float4 v = *(const float4*)&w[idx];
        half4v h = {(_Float16)v.x, (_Float16)v.y, (_Float16)v.z, (_Float16)v.w};
        *(half4v*)&o[idx] = h;
    } else {
        int tid = threadIdx.x;
        if (blockIdx.x == 0) {
            #pragma unroll
            for (int k = 0; k < 4; k++) gcur[tid + k * 256] = 0;       // 1024 ints
        } else if (blockIdx.x == 1) {
            if (tid < 128) hs1[(size_t)n * D + tid] = (_Float16)0.f;   // sentinel row
        } else if (blockIdx.x == 2) {
            if (tid < 128) hs2[(size_t)n * D + tid] = (_Float16)0.f;
        }
    }
}

// ------------------------------------------------- MFMA GEMM, fp32 A (r7 form: 2 row-tiles/wave).
__global__ __launch_bounds__(256) void gemm_f32a_kernel(const float* __restrict__ A,
                                                        const _Float16* __restrict__ Wt,
                                                        const float* __restrict__ dinv1,
                                                        const float* __restrict__ dinv2,
                                                        _Float16* __restrict__ hs1,
                                                        _Float16* __restrict__ hs2, int n) {
    __shared__ float trs[4][16 * TRS];
    int tid = threadIdx.x;
    int wv = tid >> 6, lane = tid & 63;
    int m = lane & 15, q = lane >> 4;
    int row0 = blockIdx.x * 128 + wv * 32;
    size_t ar0 = (size_t)min(row0 + m, n - 1) * D;
    size_t ar1 = (size_t)min(row0 + 16 + m, n - 1) * D;
    fx4 acc[2][8];
    #pragma unroll
    for (int t = 0; t < 2; t++)
        #pragma unroll
        for (int ct = 0; ct < 8; ct++) acc[t][ct] = (fx4){0.f, 0.f, 0.f, 0.f};
    #pragma unroll
    for (int ks = 0; ks < 4; ks++) {
        int k0 = ks * 32 + q * 8;
        half8 bf[8];
        #pragma unroll
        for (int ct = 0; ct < 8; ct++)
            bf[ct] = *(const half8*)&Wt[(size_t)(ct * 16 + m) * D + k0];
        float4 u0 = *(const float4*)&A[ar0 + k0];
        float4 u1 = *(const float4*)&A[ar0 + k0 + 4];
        half8 a0 = {(_Float16)u0.x, (_Float16)u0.y, (_Float16)u0.z, (_Float16)u0.w,
                    (_Float16)u1.x, (_Float16)u1.y, (_Float16)u1.z, (_Float16)u1.w};
        float4 v0 = *(const float4*)&A[ar1 + k0];
        float4 v1 = *(const float4*)&A[ar1 + k0 + 4];
        half8 a1 = {(_Float16)v0.x, (_Float16)v0.y, (_Float16)v0.z, (_Float16)v0.w,
                    (_Float16)v1.x, (_Float16)v1.y, (_Float16)v1.z, (_Float16)v1.w};
        #pragma unroll
        for (int ct = 0; ct < 8; ct++) {
            acc[0][ct] = __builtin_amdgcn_mfma_f32_16x16x32_f16(a0, bf[ct], acc[0][ct], 0, 0, 0);
            acc[1][ct] = __builtin_amdgcn_mfma_f32_16x16x32_f16(a1, bf[ct], acc[1][ct], 0, 0, 0);
        }
    }
    float* Wl = trs[wv];
    #pragma unroll
    for (int t = 0; t < 2; t++) {
        #pragma unroll
        for (int reg = 0; reg < 4; reg++)
            #pragma unroll
            for (int ct = 0; ct < 8; ct++)
                Wl[(q * 4 + reg) * TRS + ct * 16 + m] = acc[t][ct][reg];
        int r = row0 + t * 16 + m;
        if (r < n) {
            float s1 = dinv1[r], s2 = dinv2[r];
            size_t rr = (size_t)r * D;
            #pragma unroll
            for (int ks = 0; ks < 4; ks++) {
                int c0 = ks * 32 + q * 8;
                float4 p0 = *(const float4*)&Wl[m * TRS + c0];
                float4 p1 = *(const float4*)&Wl[m * TRS + c0 + 4];
                float pv[8] = {p0.x, p0.y, p0.z, p0.w, p1.x, p1.y, p1.z, p1.w};
                half8 h1v, h2v;
                #pragma unroll
                for (int j = 0; j < 8; j++) {
                    h1v[j] = (_Float16)(s1 * pv[j]);
                    h2v[j] = (_Float16)(s2 * pv[j]);
                }
                *(half8*)&hs1[rr + c0] = h1v;
                *(half8*)&hs2[rr + c0] = h2v;
            }
        }
    }
}

// ------------------------------------------------- MFMA GEMM, fp16 A (r7 form)
__global__ __launch_bounds__(256) void gemm_f16a_kernel(const _Float16* __restrict__ A,
                                                        const _Float16* __restrict__ Wt,
                                                        const float* __restrict__ dinv1,
                                                        const float* __restrict__ dinv2,
                                                        _Float16* __restrict__ hs1,
                                                        _Float16* __restrict__ hs2, int n) {
    __shared__ float trs[4][16 * TRS];
    int tid = threadIdx.x;
    int wv = tid >> 6, lane = tid & 63;
    int m = lane & 15, q = lane >> 4;
    int row0 = blockIdx.x * 128 + wv * 32;
    size_t ar0 = (size_t)min(row0 + m, n - 1) * D;
    size_t ar1 = (size_t)min(row0 + 16 + m, n - 1) * D;
    fx4 acc[2][8];
    #pragma unroll
    for (int t = 0; t < 2; t++)
        #pragma unroll
        for (int ct = 0; ct < 8; ct++) acc[t][ct] = (fx4){0.f, 0.f, 0.f, 0.f};
    #pragma unroll
    for (int ks = 0; ks < 4; ks++) {
        int k0 = ks * 32 + q * 8;
        half8 bf[8];
        #pragma unroll
        for (int ct = 0; ct < 8; ct++)
            bf[ct] = *(const half8*)&Wt[(size_t)(ct * 16 + m) * D + k0];
        half8 a0 = *(const half8*)&A[ar0 + k0];
        half8 a1 = *(const half8*)&A[ar1 + k0];
        #pragma unroll
        for (int ct = 0; ct < 8; ct++) {
            acc[0][ct] = __builtin_amdgcn_mfma_f32_16x16x32_f16(a0, bf[ct], acc[0][ct], 0, 0, 0);
            acc[1][ct] = __builtin_amdgcn_mfma_f32_16x16x32_f16(a1, bf[ct], acc[1][ct], 0, 0, 0);
        }
    }
    float* Wl = trs[wv];
    #pragma unroll
    for (int t = 0; t < 2; t++) {
        #pragma unroll
        for (int reg = 0; reg < 4; reg++)
            #pragma unroll
            for (int ct = 0; ct < 8; ct++)
                Wl[(q * 4 + reg) * TRS + ct * 16 + m] = acc[t][ct][reg];
        int r = row0 + t * 16 + m;
        if (r < n) {
            float s1 = dinv1[r], s2 = dinv2[r];
            size_t rr = (size_t)r * D;
            #pragma unroll
            for (int ks = 0; ks < 4; ks++) {
                int c0 = ks * 32 + q * 8;
                float4 p0 = *(const float4*)&Wl[m * TRS + c0];
                float4 p1 = *(const float4*)&Wl[m * TRS + c0 + 4];
                float pv[8] = {p0.x, p0.y, p0.z, p0.w, p1.x, p1.y, p1.z, p1.w};
                half8 h1v, h2v;
                #pragma unroll
                for (int j = 0; j < 8; j++) {
                    h1v[j] = (_Float16)(s1 * pv[j]);
                    h2v[j] = (_Float16)(s2 * pv[j]);
                }
                *(half8*)&hs1[rr + c0] = h1v;
                *(half8*)&hs2[rr + c0] = h2v;
            }
        }
    }
}

// ---------------------------------------- aggregation: QUARTER-WAVE rows (uint4/lane,
// 16 lanes/row -> 1 VMEM inst = 4 rows). Per 16 edges: 5 VMEM insts vs 9 in the
// half-wave form — probes the VMEM-instruction-issue bound (bytes/lines unchanged).
__global__ __launch_bounds__(256) void aggregate2_kernel(const __half* __restrict__ hs1g,
                                                         const __half* __restrict__ hs2g,
                                                         const int* __restrict__ ip1,
                                                         const int* __restrict__ ipe1,
                                                         const unsigned short* __restrict__ adj1,
                                                         const float* __restrict__ dinv1,
                                                         const int* __restrict__ ip2,
                                                         const int* __restrict__ ipe2,
                                                         const unsigned short* __restrict__ adj2,
                                                         const float* __restrict__ dinv2,
                                                         const float* __restrict__ bias,
                                                         _Float16* __restrict__ out1,
                                                         _Float16* __restrict__ out2, int n) {
    const __half* hs = blockIdx.y ? hs2g : hs1g;
    const int* ip  = blockIdx.y ? ip2 : ip1;
    const int* ipe = blockIdx.y ? ipe2 : ipe1;
    const unsigned short* adj = blockIdx.y ? adj2 : adj1;
    const float* dinv = blockIdx.y ? dinv2 : dinv1;
    _Float16* out = blockIdx.y ? out2 : out1;
    int wid = threadIdx.x >> 6, lane = threadIdx.x & 63;
    int g = lane >> 4, l16 = lane & 15;      // group 0..3, lane-in-group
    int i = blockIdx.x * 4 + wid;
    if (i >= n) return;
    int beg = ip[i], endp = ipe[i];
    int fbase = 8 * l16;                     // this lane's 8-feature segment
    float acc0 = 0.f, acc1 = 0.f, acc2 = 0.f, acc3 = 0.f;
    float acc4 = 0.f, acc5 = 0.f, acc6 = 0.f, acc7 = 0.f;
    if (beg < endp) {
        int goff = g << 2;                   // group g handles entries j+4g..j+4g+3
        int j = beg;
        uint2 av = *(const uint2*)&adj[j + goff];
        while (true) {
            int jn = j + 16;
            int jp = jn < endp ? jn : j;     // clamp: last iter re-loads current (independent)
            uint2 nav = *(const uint2*)&adj[jp + goff];
            int s0 = av.x & 0xffff, s1 = av.x >> 16;
            int s2 = av.y & 0xffff, s3 = av.y >> 16;
            uint4 r0 = *(const uint4*)&hs[(s0 << 7) + fbase];
            uint4 r1 = *(const uint4*)&hs[(s1 << 7) + fbase];
            uint4 r2 = *(const uint4*)&hs[(s2 << 7) + fbase];
            uint4 r3 = *(const uint4*)&hs[(s3 << 7) + fbase];
            float2 p;
            p = __half22float2(*(__half2*)&r0.x); acc0 += p.x; acc1 += p.y;
            p = __half22float2(*(__half2*)&r0.y); acc2 += p.x; acc3 += p.y;
            p = __half22float2(*(__half2*)&r0.z); acc4 += p.x; acc5 += p.y;
            p = __half22float2(*(__half2*)&r0.w); acc6 += p.x; acc7 += p.y;
            p = __half22float2(*(__half2*)&r1.x); acc0 += p.x; acc1 += p.y;
            p = __half22float2(*(__half2*)&r1.y); acc2 += p.x; acc3 += p.y;
            p = __half22float2(*(__half2*)&r1.z); acc4 += p.x; acc5 += p.y;
            p = __half22float2(*(__half2*)&r1.w); acc6 += p.x; acc7 += p.y;
            p = __half22float2(*(__half2*)&r2.x); acc0 += p.x; acc1 += p.y;
            p = __half22float2(*(__half2*)&r2.y); acc2 += p.x; acc3 += p.y;
            p = __half22float2(*(__half2*)&r2.z); acc4 += p.x; acc5 += p.y;
            p = __half22float2(*(__half2*)&r2.w); acc6 += p.x; acc7 += p.y;
            p = __half22float2(*(__half2*)&r3.x); acc0 += p.x; acc1 += p.y;
            p = __half22float2(*(__half2*)&r3.y); acc2 += p.x; acc3 += p.y;
            p = __half22float2(*(__half2*)&r3.z); acc4 += p.x; acc5 += p.y;
            p = __half22float2(*(__half2*)&r3.w); acc6 += p.x; acc7 += p.y;
            if (jn >= endp) break;
            av = nav; j = jn;
        }
    }
    // reduce across the 4 groups (lanes ±16, ±32) — each lane ends with full sums
    acc0 += __shfl_xor(acc0, 16, 64); acc0 += __shfl_xor(acc0, 32, 64);
    acc1 += __shfl_xor(acc1, 16, 64); acc1 += __shfl_xor(acc1, 32, 64);
    acc2 += __shfl_xor(acc2, 16, 64); acc2 += __shfl_xor(acc2, 32, 64);
    acc3 += __shfl_xor(acc3, 16, 64); acc3 += __shfl_xor(acc3, 32, 64);
    acc4 += __shfl_xor(acc4, 16, 64); acc4 += __shfl_xor(acc4, 32, 64);
    acc5 += __shfl_xor(acc5, 16, 64); acc5 += __shfl_xor(acc5, 32, 64);
    acc6 += __shfl_xor(acc6, 16, 64); acc6 += __shfl_xor(acc6, 32, 64);
    acc7 += __shfl_xor(acc7, 16, 64); acc7 += __shfl_xor(acc7, 32, 64);
    // epilogue: lane (g,l16) finishes features fbase+2g, fbase+2g+1 (explicit select, no
    // runtime-indexed array -> stays in registers)
    float ax, ay;
    if (g == 0)      { ax = acc0; ay = acc1; }
    else if (g == 1) { ax = acc2; ay = acc3; }
    else if (g == 2) { ax = acc4; ay = acc5; }
    else             { ax = acc6; ay = acc7; }
    float di = dinv[i];
    int fo = fbase + 2 * g;
    int off = (i << 7) + fo;
    unsigned int rs = *(const unsigned int*)&hs[off];
    float2 sv = __half22float2(*(const __half2*)&rs);
    float2 bv = *(const float2*)&bias[fo];
    float r0f = fmaxf(di * (ax + sv.x) + bv.x, 0.f);
    float r1f = fmaxf(di * (ay + sv.y) + bv.y, 0.f);
    __half2 hv = __floats2half2_rn(r0f, r1f);
    *(__half2*)&out[off] = hv;
}

// ---------------- fused gate (MFMA, r7 form): out = g*o1 + (1-g)*o2
__global__ __launch_bounds__(256) void gate_mfma_kernel(const _Float16* __restrict__ o1,
                                                        const _Float16* __restrict__ o2,
                                                        const _Float16* __restrict__ w1,
                                                        const _Float16* __restrict__ w2,
                                                        const float* __restrict__ b,
                                                        float* __restrict__ out32,
                                                        _Float16* __restrict__ out16,
                                                        int write16, int n) {
    __shared__ float trs[4][16 * TRS];
    int tid = threadIdx.x;
    int wv = tid >> 6, lane = tid & 63;
    int m = lane & 15, q = lane >> 4;
    int row0 = blockIdx.x * 128 + wv * 32;
    size_t ar0 = (size_t)min(row0 + m, n - 1) * D;
    size_t ar1 = (size_t)min(row0 + 16 + m, n - 1) * D;
    fx4 acc[2][8];
    #pragma unroll
    for (int t = 0; t < 2; t++)
        #pragma unroll
        for (int ct = 0; ct < 8; ct++) acc[t][ct] = (fx4){0.f, 0.f, 0.f, 0.f};
    #pragma unroll
    for (int ks = 0; ks < 4; ks++) {
        int k0 = ks * 32 + q * 8;
        half8 bf1[8], bf2[8];
        #pragma unroll
        for (int ct = 0; ct < 8; ct++) {
            bf1[ct] = *(const half8*)&w1[(size_t)(ct * 16 + m) * D + k0];
            bf2[ct] = *(const half8*)&w2[(size_t)(ct * 16 + m) * D + k0];
        }
        half8 a10 = *(const half8*)&o1[ar0 + k0];
        half8 a20 = *(const half8*)&o2[ar0 + k0];
        half8 a11 = *(const half8*)&o1[ar1 + k0];
        half8 a21 = *(const half8*)&o2[ar1 + k0];
        #pragma unroll
        for (int ct = 0; ct < 8; ct++) {
            acc[0][ct] = __builtin_amdgcn_mfma_f32_16x16x32_f16(a10, bf1[ct], acc[0][ct], 0, 0, 0);
            acc[0][ct] = __builtin_amdgcn_mfma_f32_16x16x32_f16(a20, bf2[ct], acc[0][ct], 0, 0, 0);
            acc[1][ct] = __builtin_amdgcn_mfma_f32_16x16x32_f16(a11, bf1[ct], acc[1][ct], 0, 0, 0);
            acc[1][ct] = __builtin_amdgcn_mfma_f32_16x16x32_f16(a21, bf2[ct], acc[1][ct], 0, 0, 0);
        }
    }
    // hoist bias: lane needs b[ks*32+q*8 .. +7] for ks=0..3
    float bb[4][8];
    #pragma unroll
    for (int ks = 0; ks < 4; ks++) {
        float4 b0 = *(const float4*)&b[ks * 32 + q * 8];
        float4 b1 = *(const float4*)&b[ks * 32 + q * 8 + 4];
        bb[ks][0] = b0.x; bb[ks][1] = b0.y; bb[ks][2] = b0.z; bb[ks][3] = b0.w;
        bb[ks][4] = b1.x; bb[ks][5] = b1.y; bb[ks][6] = b1.z; bb[ks][7] = b1.w;
    }
    float* Wl = trs[wv];
    #pragma unroll
    for (int t = 0; t < 2; t++) {
        #pragma unroll
        for (int reg = 0; reg < 4; reg++)
            #pragma unroll
            for (int ct = 0; ct < 8; ct++)
                Wl[(q * 4 + reg) * TRS + ct * 16 + m] = acc[t][ct][reg];
        int r = row0 + t * 16 + m;
        size_t rr = (size_t)min(r, n - 1) * D;
        #pragma unroll
        for (int ks = 0; ks < 4; ks++) {
            int c0 = ks * 32 + q * 8;
            float4 p0 = *(const float4*)&Wl[m * TRS + c0];
            float4 p1 = *(const float4*)&Wl[m * TRS + c0 + 4];
            half8 u1 = *(const half8*)&o1[rr + c0];
            half8 u2 = *(const half8*)&o2[rr + c0];
            float pv[8] = {p0.x, p0.y, p0.z, p0.w, p1.x, p1.y, p1.z, p1.w};
            float res[8];
            #pragma unroll
            for (int j = 0; j < 8; j++) {
                float tv = pv[j] + bb[ks][j];
                float g = 1.0f / (1.0f + __expf(-tv));
                res[j] = g * (float)u1[j] + (1.0f - g) * (float)u2[j];
            }
            if (r < n) {
                if (write16) {
                    half8 hv = {(_Float16)res[0], (_Float16)res[1], (_Float16)res[2], (_Float16)res[3],
                                (_Float16)res[4], (_Float16)res[5], (_Float16)res[6], (_Float16)res[7]};
                    *(half8*)&out16[rr + c0] = hv;
                } else {
                    *(float4*)&out32[rr + c0]     = make_float4(res[0], res[1], res[2], res[3]);
                    *(float4*)&out32[rr + c0 + 4] = make_float4(res[4], res[5], res[6], res[7]);
                }
            }
        }
    }
}

// ---------------------------------------------------------------- launch
extern "C" void kernel_launch(void* const* d_in, const int* in_sizes, int n_in,
                              void* d_out, int out_size, void* d_ws, size_t ws_size,
                              hipStream_t stream) {
    const float* x   = (const float*)d_in[0];
    const int*   eix = (const int*)d_in[1];
    const float* W1  = (const float*)d_in[2];
    const float* bc1 = (const float*)d_in[3];
    const float* W2  = (const float*)d_in[4];
    const float* bc2 = (const float*)d_in[5];
    const float* w11 = (const float*)d_in[6];
    const float* w12 = (const float*)d_in[7];
    const float* b1  = (const float*)d_in[8];
    const float* w21 = (const float*)d_in[9];
    const float* w22 = (const float*)d_in[10];
    const float* b2  = (const float*)d_in[11];
    int n = in_sizes[0] / D;
    int e = in_sizes[1] / 2;
    const int* src = eix;
    const int* dst = eix + e;

    int nb = (n + 127) >> BSH;          // 391 buckets
    int nblk = (e + SEG - 1) / SEG;     // 196 edge segments

    char* p = (char*)d_ws;
    auto alloc = [&](size_t bytes) {
        char* q = p;
        p += (bytes + 255) & ~(size_t)255;
        return q;
    };
    int* gcur1 = (int*)alloc((size_t)2 * 512 * sizeof(int));   // zeroed in prep y==6
    int* gcur2 = gcur1 + 512;
    unsigned int* rec1 = (unsigned int*)alloc((size_t)nb * RCAP * sizeof(unsigned int));
    unsigned int* rec2 = (unsigned int*)alloc((size_t)nb * RCAP * sizeof(unsigned int));
    int*   ip1   = (int*)alloc((size_t)n * sizeof(int));
    int*   ipe1  = (int*)alloc((size_t)n * sizeof(int));
    int*   ip2   = (int*)alloc((size_t)n * sizeof(int));
    int*   ipe2  = (int*)alloc((size_t)n * sizeof(int));
    float* dinv1 = (float*)alloc((size_t)(n + 1) * sizeof(float));
    float* dinv2 = (float*)alloc((size_t)(n + 1) * sizeof(float));
    unsigned short* adj1 = (unsigned short*)alloc((size_t)nb * ACAP * sizeof(unsigned short));
    unsigned short* adj2 = (unsigned short*)alloc((size_t)nb * ACAP * sizeof(unsigned short));
    _Float16* W1t  = (_Float16*)alloc((size_t)D * D * sizeof(_Float16));
    _Float16* W2t  = (_Float16*)alloc((size_t)D * D * sizeof(_Float16));
    _Float16* w11h = (_Float16*)alloc((size_t)D * D * sizeof(_Float16));
    _Float16* w12h = (_Float16*)alloc((size_t)D * D * sizeof(_Float16));
    _Float16* w21h = (_Float16*)alloc((size_t)D * D * sizeof(_Float16));
    _Float16* w22h = (_Float16*)alloc((size_t)D * D * sizeof(_Float16));
    _Float16* hs1  = (_Float16*)alloc((size_t)(n + 1) * D * sizeof(_Float16)); // +1 zero sentinel row
    _Float16* hs2  = (_Float16*)alloc((size_t)(n + 1) * D * sizeof(_Float16)); // +1 zero sentinel row
    _Float16* o1h  = (_Float16*)alloc((size_t)n * D * sizeof(_Float16));
    _Float16* o2h  = (_Float16*)alloc((size_t)n * D * sizeof(_Float16));
    _Float16* h2h  = (_Float16*)alloc((size_t)n * D * sizeof(_Float16));
    float* outF  = (float*)d_out;

    prep_kernel<<<dim3(16, 7), 256, 0, stream>>>(W1, W2, w11, w12, w21, w22,
                                                 W1t, W2t, w11h, w12h, w21h, w22h,
                                                 gcur1, hs1, hs2, n);
    scat2_kernel<<<nblk, 512, 0, stream>>>(src, dst, e, nb, gcur1, gcur2, rec1, rec2);
    fin_kernel<<<dim3(nb, 2), 256, 0, stream>>>(rec1, rec2, gcur1, gcur2,
                                                adj1, adj2, ip1, ipe1, ip2, ipe2, dinv1, dinv2, n);

    int gG = (n + 127) / 128;   // 391 blocks (128 rows/block, r7 geometry)
    int gA = (n + 3) / 4;       // 4 nodes/block (4 waves)
    // ---- layer 1
    gemm_f32a_kernel<<<gG, 256, 0, stream>>>(x, W1t, dinv1, dinv2, hs1, hs2, n);     // hs1,hs2 (fp16, pre-scaled)
    aggregate2_kernel<<<dim3(gA, 2), 256, 0, stream>>>((const __half*)hs1, (const __half*)hs2,
                                                       ip1, ipe1, adj1, dinv1,
                                                       ip2, ipe2, adj2, dinv2,
                                                       bc1, o1h, o2h, n);            // o1,o2 fp16
    gate_mfma_kernel<<<gG, 256, 0, stream>>>(o1h, o2h, w11h, w12h, b1,
                                             nullptr, h2h, 1, n);                    // h2 fp16
    // ---- layer 2
    gemm_f16a_kernel<<<gG, 256, 0, stream>>>(h2h, W2t, dinv1, dinv2, hs1, hs2, n);   // hh pre-scaled
    aggregate2_kernel<<<dim3(gA, 2), 256, 0, stream>>>((const __half*)hs1, (const __half*)hs2,
                                                       ip1, ipe1, adj1, dinv1,
                                                       ip2, ipe2, adj2, dinv2,
                                                       bc2, o1h, o2h, n);            // p1,p2 fp16
    gate_mfma_kernel<<<gG, 256, 0, stream>>>(o1h, o2h, w21h, w22h, b2, outF, nullptr, 0, n); // out fp32
}

// Round 12
// 285.387 us; speedup vs baseline: 1.2480x; 1.1007x over previous
//
#include <hip/hip_runtime.h>
#include <hip/hip_bf16.h>
#include <hip/hip_fp16.h>
#include <math.h>

#define D 128
#define SEG 4096           // edges per block in scat2 (196 blocks; SEG=1024 measured WORSE, r5)
#define BSH 7              // bucket shift: bucket = node >> 7 (128 nodes/bucket)
#define RCAP 4096          // fixed record capacity per bucket
#define ACAP 4096          // fixed adjacency capacity per bucket (16-padded lists; mean ~3050, max ~3300)
#define TRS 133            // LDS transpose row stride (fp32) -> <=2-way bank aliasing (free)

typedef _Float16 half8  __attribute__((ext_vector_type(8)));
typedef _Float16 half4v __attribute__((ext_vector_type(4)));
typedef float    fx4    __attribute__((ext_vector_type(4)));

// Stage a 128x128 fp16 matrix into XOR-swizzled LDS (byte ^= (c&7)<<4).
// Coalesced 16B global reads; balanced LDS writes. 8 iters @ 256 threads.
#define BSTAGE(Bl, Wsrc)                                                      \
    for (int i_ = threadIdx.x * 8; i_ < 16384; i_ += 2048) {                  \
        int c_ = i_ >> 7;                                                     \
        unsigned b_ = (unsigned)(i_ * 2) ^ (unsigned)((c_ & 7) << 4);         \
        *(half8*)((char*)(Bl) + b_) = *(const half8*)&(Wsrc)[i_];             \
    }

// ---------------- CSR pass 1 (r7 best-measured form): fused histogram + reservation + scatter.
__global__ __launch_bounds__(512) void scat2_kernel(const int* __restrict__ src,
                                                    const int* __restrict__ dst,
                                                    int e, int nb,
                                                    int* __restrict__ gcur1, int* __restrict__ gcur2,
                                                    unsigned int* __restrict__ rec1,
                                                    unsigned int* __restrict__ rec2) {
    __shared__ int h1[512], h2[512], o1[512], o2[512], run1[512], run2[512];
    int tid = threadIdx.x;
    for (int b = tid; b < nb; b += 512) { h1[b] = 0; h2[b] = 0; run1[b] = 0; run2[b] = 0; }
    __syncthreads();
    int s0 = blockIdx.x * SEG;
    int s1 = min(e, s0 + SEG);
    int4 sv4[2], dv4[2];
    int np[2];                       // valid edges in pack (0,4, or tail count)
    #pragma unroll
    for (int it = 0; it < 2; it++) {
        int idx = s0 + (it * 512 + tid) * 4;
        int nv = 0;
        if (idx + 3 < s1) {
            sv4[it] = *(const int4*)&src[idx];
            dv4[it] = *(const int4*)&dst[idx];
            nv = 4;
        } else if (idx < s1) {       // ragged tail
            nv = s1 - idx;
            int sv[4] = {0,0,0,0}, dv[4] = {0,0,0,0};
            for (int k = 0; k < nv; k++) { sv[k] = src[idx + k]; dv[k] = dst[idx + k]; }
            sv4[it] = make_int4(sv[0], sv[1], sv[2], sv[3]);
            dv4[it] = make_int4(dv[0], dv[1], dv[2], dv[3]);
        }
        np[it] = nv;
        int dvv[4] = {dv4[it].x, dv4[it].y, dv4[it].z, dv4[it].w};
        int svv[4] = {sv4[it].x, sv4[it].y, sv4[it].z, sv4[it].w};
        for (int k = 0; k < nv; k++) {
            atomicAdd(&h1[dvv[k] >> BSH], 1);
            atomicAdd(&h2[svv[k] >> BSH], 1);
        }
    }
    __syncthreads();
    for (int b = tid; b < nb; b += 512) {
        o1[b] = atomicAdd(&gcur1[b], h1[b]);
        o2[b] = atomicAdd(&gcur2[b], h2[b]);
    }
    __syncthreads();
    #pragma unroll
    for (int it = 0; it < 2; it++) {
        int nv = np[it];
        int dvv[4] = {dv4[it].x, dv4[it].y, dv4[it].z, dv4[it].w};
        int svv[4] = {sv4[it].x, sv4[it].y, sv4[it].z, sv4[it].w};
        for (int k = 0; k < nv; k++) {
            unsigned int sv = (unsigned int)svv[k];
            unsigned int dv = (unsigned int)dvv[k];
            int b1 = dv >> BSH, b2 = sv >> BSH;
            int p1 = o1[b1] + atomicAdd(&run1[b1], 1);
            if (p1 < RCAP) rec1[(size_t)b1 * RCAP + p1] = (dv << 16) | sv;
            int p2 = o2[b2] + atomicAdd(&run2[b2], 1);
            if (p2 < RCAP) rec2[(size_t)b2 * RCAP + p2] = (sv << 16) | dv;
        }
    }
}

// ---------------- CSR pass 2 (r10 form): per (bucket,dir) LDS-local CSR, 16-padded lists.
__global__ __launch_bounds__(256) void fin_kernel(const unsigned int* __restrict__ rec1,
                                                  const unsigned int* __restrict__ rec2,
                                                  const int* __restrict__ gcur1, const int* __restrict__ gcur2,
                                                  unsigned short* __restrict__ adj1, unsigned short* __restrict__ adj2,
                                                  int* __restrict__ ip1, int* __restrict__ ipe1,
                                                  int* __restrict__ ip2, int* __restrict__ ipe2,
                                                  float* __restrict__ dinv1, float* __restrict__ dinv2,
                                                  int n) {
    __shared__ __align__(16) unsigned int Lrec[RCAP];
    __shared__ __align__(16) unsigned short sadj[ACAP];
    __shared__ int deg[128], pscan[128], cur[128];
    __shared__ int ptot_s;
    int bkt = blockIdx.x;
    int dir = blockIdx.y;
    const unsigned int* rec = dir ? rec2 : rec1;
    const int* gc = dir ? gcur2 : gcur1;
    unsigned short* adj = dir ? adj2 : adj1;
    int* ip  = dir ? ip2 : ip1;
    int* ipe = dir ? ipe2 : ipe1;
    float* dinv = dir ? dinv2 : dinv1;

    int tid = threadIdx.x;
    int cnt = gc[bkt];
    if (cnt > RCAP) cnt = RCAP;
    size_t rbase = (size_t)bkt * RCAP;
    if (tid < 128) { deg[tid] = 0; cur[tid] = 0; }
    for (int i = tid * 4; i < cnt; i += 1024) {
        if (i + 3 < cnt) *(uint4*)&Lrec[i] = *(const uint4*)&rec[rbase + i];
        else for (int k = 0; i + k < cnt; k++) Lrec[i + k] = rec[rbase + i + k];
    }
    __syncthreads();
    int base = bkt << BSH;
    for (int i = tid * 4; i < cnt; i += 1024) {
        int lim = min(4, cnt - i);
        for (int k = 0; k < lim; k++)
            atomicAdd(&deg[(int)(Lrec[i + k] >> 16) - base], 1);
    }
    __syncthreads();
    if (tid < 64) {                      // single-wave scan of 128 padded degrees (16-pad)
        int a = (deg[2 * tid] + 15) & ~15;
        int b = (deg[2 * tid + 1] + 15) & ~15;
        int s = a + b;
        #pragma unroll
        for (int off = 1; off < 64; off <<= 1) {
            int u = __shfl_up(s, off, 64);
            if (tid >= off) s += u;
        }
        pscan[2 * tid + 1] = s;
        pscan[2 * tid]     = s - b;
        if (tid == 63) ptot_s = min(s, ACAP);
    }
    __syncthreads();
    int ptot = ptot_s;
    unsigned int nn = ((unsigned int)n << 16) | (unsigned int)n;
    uint4 fillv = make_uint4(nn, nn, nn, nn);
    for (int i = tid * 8; i < ptot; i += 2048) *(uint4*)&sadj[i] = fillv;   // sentinel fill (ptot % 16 == 0)
    __syncthreads();
    for (int i = tid; i < cnt; i += 256) {
        unsigned int r = Lrec[i];
        int l = (int)(r >> 16) - base;
        int pd = (deg[l] + 15) & ~15;
        int pos = pscan[l] - pd + atomicAdd(&cur[l], 1);
        if (pos < ACAP) sadj[pos] = (unsigned short)(r & 0xffffu);
    }
    __syncthreads();
    int gbase = bkt * ACAP;
    for (int i = tid * 8; i < ptot; i += 2048)
        *(uint4*)&adj[gbase + i] = *(const uint4*)&sadj[i];
    if (tid < 128) {
        int node = base + tid;
        if (node < n) {
            int pd = (deg[tid] + 15) & ~15;
            ip[node]  = gbase + pscan[tid] - pd;
            ipe[node] = gbase + pscan[tid];
            dinv[node] = rsqrtf((float)deg[tid] + 1.0f);
        }
    }
}

// ---------------- weight prep (merged): y=0,1 transpose W1/W2 to fp16 [c][k];
// y=2..5 fp16-convert gates; y=6 zero work (gcur, hs sentinel rows).
__global__ __launch_bounds__(256) void prep_kernel(const float* __restrict__ W1, const float* __restrict__ W2,
                                                   const float* __restrict__ w11, const float* __restrict__ w12,
                                                   const float* __restrict__ w21, const float* __restrict__ w22,
                                                   _Float16* __restrict__ T1, _Float16* __restrict__ T2,
                                                   _Float16* __restrict__ o11, _Float16* __restrict__ o12,
                                                   _Float16* __restrict__ o21, _Float16* __restrict__ o22,
                                                   int* __restrict__ gcur, _Float16* __restrict__ hs1,
                                                   _Float16* __restrict__ hs2, int n) {
    __shared__ float s[32][33];
    int which = blockIdx.y;
    if (which < 2) {
        const float* w = which ? W2 : W1;
        _Float16* t = which ? T2 : T1;
        int tk = (blockIdx.x >> 2) * 32;
        int tc = (blockIdx.x & 3) * 32;
        int lr = threadIdx.x >> 5;
        int lc = threadIdx.x & 31;
        #pragma unroll
        for (int i = 0; i < 32; i += 8)
            s[lr + i][lc] = w[(size_t)(tk + lr + i) * D + tc + lc];
        __syncthreads();
        #pragma unroll
        for (int i = 0; i < 32; i += 8)
            t[(size_t)(tc + lr + i) * D + tk + lc] = (_Float16)s[lc][lr + i];
    } else if (which < 6) {
        int wsel = which - 2;
        const float* w = (wsel == 0) ? w11 : (wsel == 1) ? w12 : (wsel == 2) ? w21 : w22;
        _Float16* o = (wsel == 0) ? o11 : (wsel == 1) ? o12 : (wsel == 2) ? o21 : o22;
        int idx = (blockIdx.x * 256 + threadIdx.x) * 4;
        float4 v = *(const float4*)&w[idx];
        half4v h = {(_Float16)v.x, (_Float16)v.y, (_Float16)v.z, (_Float16)v.w};
        *(half4v*)&o[idx] = h;
    } else {
        int tid = threadIdx.x;
        if (blockIdx.x == 0) {
            #pragma unroll
            for (int k = 0; k < 4; k++) gcur[tid + k * 256] = 0;       // 1024 ints
        } else if (blockIdx.x == 1) {
            if (tid < 128) hs1[(size_t)n * D + tid] = (_Float16)0.f;   // sentinel row
        } else if (blockIdx.x == 2) {
            if (tid < 128) hs2[(size_t)n * D + tid] = (_Float16)0.f;
        }
    }
}

// ------------------------------------------------- MFMA GEMM, fp32 A.
// B staged ONCE per block into swizzled LDS (was: every wave re-reads 2MB of B from
// L2 -> 0.78 GB/dispatch). LDS unioned with the epilogue transpose buffer.
__global__ __launch_bounds__(256) void gemm_f32a_kernel(const float* __restrict__ A,
                                                        const _Float16* __restrict__ Wt,
                                                        const float* __restrict__ dinv1,
                                                        const float* __restrict__ dinv2,
                                                        _Float16* __restrict__ hs1,
                                                        _Float16* __restrict__ hs2, int n) {
    __shared__ __align__(16) float lds[4 * 16 * TRS];   // 34048 B >= 32768 B for B
    _Float16* Bl = (_Float16*)lds;
    int tid = threadIdx.x;
    int wv = tid >> 6, lane = tid & 63;
    int m = lane & 15, q = lane >> 4;
    int row0 = blockIdx.x * 128 + wv * 32;
    size_t ar0 = (size_t)min(row0 + m, n - 1) * D;
    size_t ar1 = (size_t)min(row0 + 16 + m, n - 1) * D;
    BSTAGE(Bl, Wt);
    __syncthreads();
    fx4 acc[2][8];
    #pragma unroll
    for (int t = 0; t < 2; t++)
        #pragma unroll
        for (int ct = 0; ct < 8; ct++) acc[t][ct] = (fx4){0.f, 0.f, 0.f, 0.f};
    unsigned swz = (unsigned)((m & 7) << 4);
    #pragma unroll
    for (int ks = 0; ks < 4; ks++) {
        int k0 = ks * 32 + q * 8;
        half8 bf[8];
        #pragma unroll
        for (int ct = 0; ct < 8; ct++) {
            unsigned rb = (unsigned)((ct * 16 + m) * 256 + k0 * 2) ^ swz;
            bf[ct] = *(const half8*)((const char*)Bl + rb);
        }
        float4 u0 = *(const float4*)&A[ar0 + k0];
        float4 u1 = *(const float4*)&A[ar0 + k0 + 4];
        half8 a0 = {(_Float16)u0.x, (_Float16)u0.y, (_Float16)u0.z, (_Float16)u0.w,
                    (_Float16)u1.x, (_Float16)u1.y, (_Float16)u1.z, (_Float16)u1.w};
        float4 v0 = *(const float4*)&A[ar1 + k0];
        float4 v1 = *(const float4*)&A[ar1 + k0 + 4];
        half8 a1 = {(_Float16)v0.x, (_Float16)v0.y, (_Float16)v0.z, (_Float16)v0.w,
                    (_Float16)v1.x, (_Float16)v1.y, (_Float16)v1.z, (_Float16)v1.w};
        #pragma unroll
        for (int ct = 0; ct < 8; ct++) {
            acc[0][ct] = __builtin_amdgcn_mfma_f32_16x16x32_f16(a0, bf[ct], acc[0][ct], 0, 0, 0);
            acc[1][ct] = __builtin_amdgcn_mfma_f32_16x16x32_f16(a1, bf[ct], acc[1][ct], 0, 0, 0);
        }
    }
    __syncthreads();                    // all waves done reading B before trs overwrites it
    float* Wl = lds + wv * 16 * TRS;
    #pragma unroll
    for (int t = 0; t < 2; t++) {
        #pragma unroll
        for (int reg = 0; reg < 4; reg++)
            #pragma unroll
            for (int ct = 0; ct < 8; ct++)
                Wl[(q * 4 + reg) * TRS + ct * 16 + m] = acc[t][ct][reg];
        int r = row0 + t * 16 + m;
        if (r < n) {
            float s1 = dinv1[r], s2 = dinv2[r];
            size_t rr = (size_t)r * D;
            #pragma unroll
            for (int ks = 0; ks < 4; ks++) {
                int c0 = ks * 32 + q * 8;
                float4 p0 = *(const float4*)&Wl[m * TRS + c0];
                float4 p1 = *(const float4*)&Wl[m * TRS + c0 + 4];
                float pv[8] = {p0.x, p0.y, p0.z, p0.w, p1.x, p1.y, p1.z, p1.w};
                half8 h1v, h2v;
                #pragma unroll
                for (int j = 0; j < 8; j++) {
                    h1v[j] = (_Float16)(s1 * pv[j]);
                    h2v[j] = (_Float16)(s2 * pv[j]);
                }
                *(half8*)&hs1[rr + c0] = h1v;
                *(half8*)&hs2[rr + c0] = h2v;
            }
        }
    }
}

// ------------------------------------------------- MFMA GEMM, fp16 A (same LDS-B structure)
__global__ __launch_bounds__(256) void gemm_f16a_kernel(const _Float16* __restrict__ A,
                                                        const _Float16* __restrict__ Wt,
                                                        const float* __restrict__ dinv1,
                                                        const float* __restrict__ dinv2,
                                                        _Float16* __restrict__ hs1,
                                                        _Float16* __restrict__ hs2, int n) {
    __shared__ __align__(16) float lds[4 * 16 * TRS];
    _Float16* Bl = (_Float16*)lds;
    int tid = threadIdx.x;
    int wv = tid >> 6, lane = tid & 63;
    int m = lane & 15, q = lane >> 4;
    int row0 = blockIdx.x * 128 + wv * 32;
    size_t ar0 = (size_t)min(row0 + m, n - 1) * D;
    size_t ar1 = (size_t)min(row0 + 16 + m, n - 1) * D;
    BSTAGE(Bl, Wt);
    __syncthreads();
    fx4 acc[2][8];
    #pragma unroll
    for (int t = 0; t < 2; t++)
        #pragma unroll
        for (int ct = 0; ct < 8; ct++) acc[t][ct] = (fx4){0.f, 0.f, 0.f, 0.f};
    unsigned swz = (unsigned)((m & 7) << 4);
    #pragma unroll
    for (int ks = 0; ks < 4; ks++) {
        int k0 = ks * 32 + q * 8;
        half8 bf[8];
        #pragma unroll
        for (int ct = 0; ct < 8; ct++) {
            unsigned rb = (unsigned)((ct * 16 + m) * 256 + k0 * 2) ^ swz;
            bf[ct] = *(const half8*)((const char*)Bl + rb);
        }
        half8 a0 = *(const half8*)&A[ar0 + k0];
        half8 a1 = *(const half8*)&A[ar1 + k0];
        #pragma unroll
        for (int ct = 0; ct < 8; ct++) {
            acc[0][ct] = __builtin_amdgcn_mfma_f32_16x16x32_f16(a0, bf[ct], acc[0][ct], 0, 0, 0);
            acc[1][ct] = __builtin_amdgcn_mfma_f32_16x16x32_f16(a1, bf[ct], acc[1][ct], 0, 0, 0);
        }
    }
    __syncthreads();
    float* Wl = lds + wv * 16 * TRS;
    #pragma unroll
    for (int t = 0; t < 2; t++) {
        #pragma unroll
        for (int reg = 0; reg < 4; reg++)
            #pragma unroll
            for (int ct = 0; ct < 8; ct++)
                Wl[(q * 4 + reg) * TRS + ct * 16 + m] = acc[t][ct][reg];
        int r = row0 + t * 16 + m;
        if (r < n) {
            float s1 = dinv1[r], s2 = dinv2[r];
            size_t rr = (size_t)r * D;
            #pragma unroll
            for (int ks = 0; ks < 4; ks++) {
                int c0 = ks * 32 + q * 8;
                float4 p0 = *(const float4*)&Wl[m * TRS + c0];
                float4 p1 = *(const float4*)&Wl[m * TRS + c0 + 4];
                float pv[8] = {p0.x, p0.y, p0.z, p0.w, p1.x, p1.y, p1.z, p1.w};
                half8 h1v, h2v;
                #pragma unroll
                for (int j = 0; j < 8; j++) {
                    h1v[j] = (_Float16)(s1 * pv[j]);
                    h2v[j] = (_Float16)(s2 * pv[j]);
                }
                *(half8*)&hs1[rr + c0] = h1v;
                *(half8*)&hs2[rr + c0] = h2v;
            }
        }
    }
}

// ---------------------------------------- aggregation (r11 best form — at its
// scattered-gather floor across 9 measured variants; left untouched).
__global__ __launch_bounds__(256) void aggregate2_kernel(const __half* __restrict__ hs1g,
                                                         const __half* __restrict__ hs2g,
                                                         const int* __restrict__ ip1,
                                                         const int* __restrict__ ipe1,
                                                         const unsigned short* __restrict__ adj1,
                                                         const float* __restrict__ dinv1,
                                                         const int* __restrict__ ip2,
                                                         const int* __restrict__ ipe2,
                                                         const unsigned short* __restrict__ adj2,
                                                         const float* __restrict__ dinv2,
                                                         const float* __restrict__ bias,
                                                         _Float16* __restrict__ out1,
                                                         _Float16* __restrict__ out2, int n) {
    const __half* hs = blockIdx.y ? hs2g : hs1g;
    const int* ip  = blockIdx.y ? ip2 : ip1;
    const int* ipe = blockIdx.y ? ipe2 : ipe1;
    const unsigned short* adj = blockIdx.y ? adj2 : adj1;
    const float* dinv = blockIdx.y ? dinv2 : dinv1;
    _Float16* out = blockIdx.y ? out2 : out1;
    int wid = threadIdx.x >> 6, lane = threadIdx.x & 63;
    int g = lane >> 4, l16 = lane & 15;      // group 0..3, lane-in-group
    int i = blockIdx.x * 4 + wid;
    if (i >= n) return;
    int beg = ip[i], endp = ipe[i];
    int fbase = 8 * l16;                     // this lane's 8-feature segment
    float acc0 = 0.f, acc1 = 0.f, acc2 = 0.f, acc3 = 0.f;
    float acc4 = 0.f, acc5 = 0.f, acc6 = 0.f, acc7 = 0.f;
    if (beg < endp) {
        int goff = g << 2;                   // group g handles entries j+4g..j+4g+3
        int j = beg;
        uint2 av = *(const uint2*)&adj[j + goff];
        while (true) {
            int jn = j + 16;
            int jp = jn < endp ? jn : j;     // clamp: last iter re-loads current (independent)
            uint2 nav = *(const uint2*)&adj[jp + goff];
            int s0 = av.x & 0xffff, s1 = av.x >> 16;
            int s2 = av.y & 0xffff, s3 = av.y >> 16;
            uint4 r0 = *(const uint4*)&hs[(s0 << 7) + fbase];
            uint4 r1 = *(const uint4*)&hs[(s1 << 7) + fbase];
            uint4 r2 = *(const uint4*)&hs[(s2 << 7) + fbase];
            uint4 r3 = *(const uint4*)&hs[(s3 << 7) + fbase];
            float2 p;
            p = __half22float2(*(__half2*)&r0.x); acc0 += p.x; acc1 += p.y;
            p = __half22float2(*(__half2*)&r0.y); acc2 += p.x; acc3 += p.y;
            p = __half22float2(*(__half2*)&r0.z); acc4 += p.x; acc5 += p.y;
            p = __half22float2(*(__half2*)&r0.w); acc6 += p.x; acc7 += p.y;
            p = __half22float2(*(__half2*)&r1.x); acc0 += p.x; acc1 += p.y;
            p = __half22float2(*(__half2*)&r1.y); acc2 += p.x; acc3 += p.y;
            p = __half22float2(*(__half2*)&r1.z); acc4 += p.x; acc5 += p.y;
            p = __half22float2(*(__half2*)&r1.w); acc6 += p.x; acc7 += p.y;
            p = __half22float2(*(__half2*)&r2.x); acc0 += p.x; acc1 += p.y;
            p = __half22float2(*(__half2*)&r2.y); acc2 += p.x; acc3 += p.y;
            p = __half22float2(*(__half2*)&r2.z); acc4 += p.x; acc5 += p.y;
            p = __half22float2(*(__half2*)&r2.w); acc6 += p.x; acc7 += p.y;
            p = __half22float2(*(__half2*)&r3.x); acc0 += p.x; acc1 += p.y;
            p = __half22float2(*(__half2*)&r3.y); acc2 += p.x; acc3 += p.y;
            p = __half22float2(*(__half2*)&r3.z); acc4 += p.x; acc5 += p.y;
            p = __half22float2(*(__half2*)&r3.w); acc6 += p.x; acc7 += p.y;
            if (jn >= endp) break;
            av = nav; j = jn;
        }
    }
    // reduce across the 4 groups (lanes ±16, ±32) — each lane ends with full sums
    acc0 += __shfl_xor(acc0, 16, 64); acc0 += __shfl_xor(acc0, 32, 64);
    acc1 += __shfl_xor(acc1, 16, 64); acc1 += __shfl_xor(acc1, 32, 64);
    acc2 += __shfl_xor(acc2, 16, 64); acc2 += __shfl_xor(acc2, 32, 64);
    acc3 += __shfl_xor(acc3, 16, 64); acc3 += __shfl_xor(acc3, 32, 64);
    acc4 += __shfl_xor(acc4, 16, 64); acc4 += __shfl_xor(acc4, 32, 64);
    acc5 += __shfl_xor(acc5, 16, 64); acc5 += __shfl_xor(acc5, 32, 64);
    acc6 += __shfl_xor(acc6, 16, 64); acc6 += __shfl_xor(acc6, 32, 64);
    acc7 += __shfl_xor(acc7, 16, 64); acc7 += __shfl_xor(acc7, 32, 64);
    // epilogue: lane (g,l16) finishes features fbase+2g, fbase+2g+1 (explicit select)
    float ax, ay;
    if (g == 0)      { ax = acc0; ay = acc1; }
    else if (g == 1) { ax = acc2; ay = acc3; }
    else if (g == 2) { ax = acc4; ay = acc5; }
    else             { ax = acc6; ay = acc7; }
    float di = dinv[i];
    int fo = fbase + 2 * g;
    int off = (i << 7) + fo;
    unsigned int rs = *(const unsigned int*)&hs[off];
    float2 sv = __half22float2(*(const __half2*)&rs);
    float2 bv = *(const float2*)&bias[fo];
    float r0f = fmaxf(di * (ax + sv.x) + bv.x, 0.f);
    float r1f = fmaxf(di * (ay + sv.y) + bv.y, 0.f);
    __half2 hv = __floats2half2_rn(r0f, r1f);
    *(__half2*)&out[off] = hv;
}

// ---------------- fused gate (MFMA): out = g*o1 + (1-g)*o2.
// TWO-PASS LDS-B: stage w1 -> K-loop over o1; stage w2 -> K-loop over o2 (accumulate).
// Keeps LDS at 34KB (same occupancy); eliminates 1.56 GB/dispatch of L2 B-reads.
__global__ __launch_bounds__(256) void gate_mfma_kernel(const _Float16* __restrict__ o1,
                                                        const _Float16* __restrict__ o2,
                                                        const _Float16* __restrict__ w1,
                                                        const _Float16* __restrict__ w2,
                                                        const float* __restrict__ b,
                                                        float* __restrict__ out32,
                                                        _Float16* __restrict__ out16,
                                                        int write16, int n) {
    __shared__ __align__(16) float lds[4 * 16 * TRS];
    _Float16* Bl = (_Float16*)lds;
    int tid = threadIdx.x;
    int wv = tid >> 6, lane = tid & 63;
    int m = lane & 15, q = lane >> 4;
    int row0 = blockIdx.x * 128 + wv * 32;
    size_t ar0 = (size_t)min(row0 + m, n - 1) * D;
    size_t ar1 = (size_t)min(row0 + 16 + m, n - 1) * D;
    fx4 acc[2][8];
    #pragma unroll
    for (int t = 0; t < 2; t++)
        #pragma unroll
        for (int ct = 0; ct < 8; ct++) acc[t][ct] = (fx4){0.f, 0.f, 0.f, 0.f};
    unsigned swz = (unsigned)((m & 7) << 4);
    // ---- pass 1: o1 @ w1^T
    BSTAGE(Bl, w1);
    __syncthreads();
    #pragma unroll
    for (int ks = 0; ks < 4; ks++) {
        int k0 = ks * 32 + q * 8;
        half8 bf[8];
        #pragma unroll
        for (int ct = 0; ct < 8; ct++) {
            unsigned rb = (unsigned)((ct * 16 + m) * 256 + k0 * 2) ^ swz;
            bf[ct] = *(const half8*)((const char*)Bl + rb);
        }
        half8 a10 = *(const half8*)&o1[ar0 + k0];
        half8 a11 = *(const half8*)&o1[ar1 + k0];
        #pragma unroll
        for (int ct = 0; ct < 8; ct++) {
            acc[0][ct] = __builtin_amdgcn_mfma_f32_16x16x32_f16(a10, bf[ct], acc[0][ct], 0, 0, 0);
            acc[1][ct] = __builtin_amdgcn_mfma_f32_16x16x32_f16(a11, bf[ct], acc[1][ct], 0, 0, 0);
        }
    }
    __syncthreads();
    // ---- pass 2: + o2 @ w2^T
    BSTAGE(Bl, w2);
    __syncthreads();
    #pragma unroll
    for (int ks = 0; ks < 4; ks++) {
        int k0 = ks * 32 + q * 8;
        half8 bf[8];
        #pragma unroll
        for (int ct = 0; ct < 8; ct++) {
            unsigned rb = (unsigned)((ct * 16 + m) * 256 + k0 * 2) ^ swz;
            bf[ct] = *(const half8*)((const char*)Bl + rb);
        }
        half8 a20 = *(const half8*)&o2[ar0 + k0];
        half8 a21 = *(const half8*)&o2[ar1 + k0];
        #pragma unroll
        for (int ct = 0; ct < 8; ct++) {
            acc[0][ct] = __builtin_amdgcn_mfma_f32_16x16x32_f16(a20, bf[ct], acc[0][ct], 0, 0, 0);
            acc[1][ct] = __builtin_amdgcn_mfma_f32_16x16x32_f16(a21, bf[ct], acc[1][ct], 0, 0, 0);
        }
    }
    __syncthreads();                    // B no longer needed; trs may overwrite
    // hoist bias: lane needs b[ks*32+q*8 .. +7] for ks=0..3
    float bb[4][8];
    #pragma unroll
    for (int ks = 0; ks < 4; ks++) {
        float4 b0 = *(const float4*)&b[ks * 32 + q * 8];
        float4 b1 = *(const float4*)&b[ks * 32 + q * 8 + 4];
        bb[ks][0] = b0.x; bb[ks][1] = b0.y; bb[ks][2] = b0.z; bb[ks][3] = b0.w;
        bb[ks][4] = b1.x; bb[ks][5] = b1.y; bb[ks][6] = b1.z; bb[ks][7] = b1.w;
    }
    float* Wl = lds + wv * 16 * TRS;
    #pragma unroll
    for (int t = 0; t < 2; t++) {
        #pragma unroll
        for (int reg = 0; reg < 4; reg++)
            #pragma unroll
            for (int ct = 0; ct < 8; ct++)
                Wl[(q * 4 + reg) * TRS + ct * 16 + m] = acc[t][ct][reg];
        int r = row0 + t * 16 + m;
        size_t rr = (size_t)min(r, n - 1) * D;
        #pragma unroll
        for (int ks = 0; ks < 4; ks++) {
            int c0 = ks * 32 + q * 8;
            float4 p0 = *(const float4*)&Wl[m * TRS + c0];
            float4 p1 = *(const float4*)&Wl[m * TRS + c0 + 4];
            half8 u1 = *(const half8*)&o1[rr + c0];
            half8 u2 = *(const half8*)&o2[rr + c0];
            float pv[8] = {p0.x, p0.y, p0.z, p0.w, p1.x, p1.y, p1.z, p1.w};
            float res[8];
            #pragma unroll
            for (int j = 0; j < 8; j++) {
                float tv = pv[j] + bb[ks][j];
                float g = 1.0f / (1.0f + __expf(-tv));
                res[j] = g * (float)u1[j] + (1.0f - g) * (float)u2[j];
            }
            if (r < n) {
                if (write16) {
                    half8 hv = {(_Float16)res[0], (_Float16)res[1], (_Float16)res[2], (_Float16)res[3],
                                (_Float16)res[4], (_Float16)res[5], (_Float16)res[6], (_Float16)res[7]};
                    *(half8*)&out16[rr + c0] = hv;
                } else {
                    *(float4*)&out32[rr + c0]     = make_float4(res[0], res[1], res[2], res[3]);
                    *(float4*)&out32[rr + c0 + 4] = make_float4(res[4], res[5], res[6], res[7]);
                }
            }
        }
    }
}

// ---------------------------------------------------------------- launch
extern "C" void kernel_launch(void* const* d_in, const int* in_sizes, int n_in,
                              void* d_out, int out_size, void* d_ws, size_t ws_size,
                              hipStream_t stream) {
    const float* x   = (const float*)d_in[0];
    const int*   eix = (const int*)d_in[1];
    const float* W1  = (const float*)d_in[2];
    const float* bc1 = (const float*)d_in[3];
    const float* W2  = (const float*)d_in[4];
    const float* bc2 = (const float*)d_in[5];
    const float* w11 = (const float*)d_in[6];
    const float* w12 = (const float*)d_in[7];
    const float* b1  = (const float*)d_in[8];
    const float* w21 = (const float*)d_in[9];
    const float* w22 = (const float*)d_in[10];
    const float* b2  = (const float*)d_in[11];
    int n = in_sizes[0] / D;
    int e = in_sizes[1] / 2;
    const int* src = eix;
    const int* dst = eix + e;

    int nb = (n + 127) >> BSH;          // 391 buckets
    int nblk = (e + SEG - 1) / SEG;     // 196 edge segments

    char* p = (char*)d_ws;
    auto alloc = [&](size_t bytes) {
        char* q = p;
        p += (bytes + 255) & ~(size_t)255;
        return q;
    };
    int* gcur1 = (int*)alloc((size_t)2 * 512 * sizeof(int));   // zeroed in prep y==6
    int* gcur2 = gcur1 + 512;
    unsigned int* rec1 = (unsigned int*)alloc((size_t)nb * RCAP * sizeof(unsigned int));
    unsigned int* rec2 = (unsigned int*)alloc((size_t)nb * RCAP * sizeof(unsigned int));
    int*   ip1   = (int*)alloc((size_t)n * sizeof(int));
    int*   ipe1  = (int*)alloc((size_t)n * sizeof(int));
    int*   ip2   = (int*)alloc((size_t)n * sizeof(int));
    int*   ipe2  = (int*)alloc((size_t)n * sizeof(int));
    float* dinv1 = (float*)alloc((size_t)(n + 1) * sizeof(float));
    float* dinv2 = (float*)alloc((size_t)(n + 1) * sizeof(float));
    unsigned short* adj1 = (unsigned short*)alloc((size_t)nb * ACAP * sizeof(unsigned short));
    unsigned short* adj2 = (unsigned short*)alloc((size_t)nb * ACAP * sizeof(unsigned short));
    _Float16* W1t  = (_Float16*)alloc((size_t)D * D * sizeof(_Float16));
    _Float16* W2t  = (_Float16*)alloc((size_t)D * D * sizeof(_Float16));
    _Float16* w11h = (_Float16*)alloc((size_t)D * D * sizeof(_Float16));
    _Float16* w12h = (_Float16*)alloc((size_t)D * D * sizeof(_Float16));
    _Float16* w21h = (_Float16*)alloc((size_t)D * D * sizeof(_Float16));
    _Float16* w22h = (_Float16*)alloc((size_t)D * D * sizeof(_Float16));
    _Float16* hs1  = (_Float16*)alloc((size_t)(n + 1) * D * sizeof(_Float16)); // +1 zero sentinel row
    _Float16* hs2  = (_Float16*)alloc((size_t)(n + 1) * D * sizeof(_Float16)); // +1 zero sentinel row
    _Float16* o1h  = (_Float16*)alloc((size_t)n * D * sizeof(_Float16));
    _Float16* o2h  = (_Float16*)alloc((size_t)n * D * sizeof(_Float16));
    _Float16* h2h  = (_Float16*)alloc((size_t)n * D * sizeof(_Float16));
    float* outF  = (float*)d_out;

    prep_kernel<<<dim3(16, 7), 256, 0, stream>>>(W1, W2, w11, w12, w21, w22,
                                                 W1t, W2t, w11h, w12h, w21h, w22h,
                                                 gcur1, hs1, hs2, n);
    scat2_kernel<<<nblk, 512, 0, stream>>>(src, dst, e, nb, gcur1, gcur2, rec1, rec2);
    fin_kernel<<<dim3(nb, 2), 256, 0, stream>>>(rec1, rec2, gcur1, gcur2,
                                                adj1, adj2, ip1, ipe1, ip2, ipe2, dinv1, dinv2, n);

    int gG = (n + 127) / 128;   // 391 blocks (128 rows/block, r7 geometry)
    int gA = (n + 3) / 4;       // 4 nodes/block (4 waves)
    // ---- layer 1
    gemm_f32a_kernel<<<gG, 256, 0, stream>>>(x, W1t, dinv1, dinv2, hs1, hs2, n);     // hs1,hs2 (fp16, pre-scaled)
    aggregate2_kernel<<<dim3(gA, 2), 256, 0, stream>>>((const __half*)hs1, (const __half*)hs2,
                                                       ip1, ipe1, adj1, dinv1,
                                                       ip2, ipe2, adj2, dinv2,
                                                       bc1, o1h, o2h, n);            // o1,o2 fp16
    gate_mfma_kernel<<<gG, 256, 0, stream>>>(o1h, o2h, w11h, w12h, b1,
                                             nullptr, h2h, 1, n);                    // h2 fp16
    // ---- layer 2
    gemm_f16a_kernel<<<gG, 256, 0, stream>>>(h2h, W2t, dinv1, dinv2, hs1, hs2, n);   // hh pre-scaled
    aggregate2_kernel<<<dim3(gA, 2), 256, 0, stream>>>((const __half*)hs1, (const __half*)hs2,
                                                       ip1, ipe1, adj1, dinv1,
                                                       ip2, ipe2, adj2, dinv2,
                                                       bc2, o1h, o2h, n);            // p1,p2 fp16
    gate_mfma_kernel<<<gG, 256, 0, stream>>>(o1h, o2h, w21h, w22h, b2, outF, nullptr, 0, n); // out fp32
}